// Round 7
// baseline (484.160 us; speedup 1.0000x reference)
//
#include <hip/hip_runtime.h>
#include <math.h>

#define B_ 16
#define A_ 32
#define G_ 512
#define S_ 4096
#define M_ 8
#define BS_ 65536
#define KC_ 640      // concat K: 512 normed + 100 OH + 28 pad
#define NG_ 1536
#define SMH 16384    // halfs per LDS buffer per matrix (256 rows x 64 halfs)

typedef _Float16 half8 __attribute__((ext_vector_type(8)));
typedef _Float16 half4v __attribute__((ext_vector_type(4)));
typedef _Float16 half2v __attribute__((ext_vector_type(2)));
typedef float floatx4 __attribute__((ext_vector_type(4)));

typedef const __attribute__((address_space(1))) void* gas_t;
typedef __attribute__((address_space(3))) void* las_t;

// ---------------- helpers ----------------
__device__ __forceinline__ float wave_sum_f(float v){
#pragma unroll
  for (int o = 32; o > 0; o >>= 1) v += __shfl_xor(v, o);
  return v;
}
__device__ __forceinline__ float wave_max_f(float v){
#pragma unroll
  for (int o = 32; o > 0; o >>= 1) v = fmaxf(v, __shfl_xor(v, o));
  return v;
}
__device__ __forceinline__ float sigmoidf_(float x){ return 1.f/(1.f+__expf(-x)); }
__device__ __forceinline__ float tanhf_(float x){ return 1.f - 2.f/(__expf(2.f*x)+1.f); }

// ---------------- K0a: fp32 -> fp16 convert, 3 G*G matrices ----------------
__global__ __launch_bounds__(256) void k_cvt3(const float* __restrict__ s0,
                                              const float* __restrict__ s1,
                                              const float* __restrict__ s2,
                                              _Float16* __restrict__ d){
  const float* s = (blockIdx.y == 0) ? s0 : (blockIdx.y == 1) ? s1 : s2;
  int i = (blockIdx.x*256 + threadIdx.x)*4;
  if (i >= G_*G_) return;
  float4 v = *(const float4*)(s+i);
  half4v o; o[0]=(_Float16)v.x; o[1]=(_Float16)v.y; o[2]=(_Float16)v.z; o[3]=(_Float16)v.w;
  *(half4v*)(d + (size_t)blockIdx.y*G_*G_ + i) = o;
}

// ---------------- K0b: build Wcat[1536][640] = [W_hh | W_ih | 0] ------------
__global__ __launch_bounds__(64) void k_buildw(const float* __restrict__ Whh,
                                               const float* __restrict__ Wih,
                                               _Float16* __restrict__ Wcat){
  int j = blockIdx.x;
  for (int p = threadIdx.x; p < KC_; p += 64){
    float v = 0.f;
    if (p < 512) v = Whh[(size_t)j*512 + p];
    else if (p < 612) v = Wih[(size_t)j*100 + (p - 512)];
    Wcat[(size_t)j*KC_ + p] = (_Float16)v;
  }
}

// ---------------- K1: MFMA prep — swvs GEMM + LN + counts + OH --------------
__global__ __launch_bounds__(256) void k_prep_mfma(
    const float* __restrict__ vf, const float* __restrict__ mask,
    const float* __restrict__ eoh, const float* __restrict__ subs,
    const float* __restrict__ ln_g, const float* __restrict__ ln_b,
    _Float16* __restrict__ Abuf){
  __shared__ _Float16 s_mvfT[G_*A_];   // [g][a], masked vf, 32 KB
  __shared__ _Float16 s_sm[128*A_];    // [s][a], raw subs, 8 KB
  __shared__ float s_m[A_];
  __shared__ float s_e[A_*5];
  __shared__ float s_ssum[128];
  __shared__ float s_red1[2][4][16];
  __shared__ float s_red2[2][4][16];
  int tid = threadIdx.x;
  int bx = blockIdx.x, b = blockIdx.y;
  int lane = tid & 63, w = tid >> 6;
  int q = lane >> 4, l15 = lane & 15;
  size_t row0 = (size_t)b*S_ + (size_t)bx*128;
  if (tid < A_)   s_m[tid] = mask[b*A_ + tid];
  if (tid < A_*5) s_e[tid] = eoh[b*A_*5 + tid];
  __syncthreads();
  {
    int p = tid & 15, gseg = tid >> 4;
    float mk0 = s_m[2*p], mk1 = s_m[2*p+1];
    const float* v0 = vf + ((size_t)b*A_ + 2*p)*G_ + gseg*32;
    const float* v1 = v0 + G_;
#pragma unroll
    for (int i = 0; i < 32; i += 4){
      float4 a = *(const float4*)(v0 + i);
      float4 c = *(const float4*)(v1 + i);
      float av[4] = {a.x, a.y, a.z, a.w};
      float cv[4] = {c.x, c.y, c.z, c.w};
#pragma unroll
      for (int j = 0; j < 4; ++j){
        half2v h; h[0] = (_Float16)(av[j]*mk0); h[1] = (_Float16)(cv[j]*mk1);
        *(half2v*)(s_mvfT + (gseg*32 + i + j)*A_ + 2*p) = h;
      }
    }
  }
  {
    int s = tid >> 1, hh = tid & 1;
    const float* sp = subs + (row0 + s)*A_ + hh*16;
    _Float16* dst = s_sm + s*A_ + hh*16;
#pragma unroll
    for (int i = 0; i < 16; i += 4){
      float4 v = *(const float4*)(sp + i);
      half4v h; h[0]=(_Float16)v.x; h[1]=(_Float16)v.y; h[2]=(_Float16)v.z; h[3]=(_Float16)v.w;
      *(half4v*)(dst + i) = h;
    }
  }
  __syncthreads();
  if (tid < 128){
    int s = tid;
    float ssum = 0.f, c0=0.f, c1=0.f, c2=0.f, c3=0.f, c4=0.f;
#pragma unroll
    for (int a = 0; a < A_; ++a){
      float v = (float)s_sm[s*A_ + a];
      ssum += v * s_m[a];
      c0 += v * s_e[a*5+0]; c1 += v * s_e[a*5+1]; c2 += v * s_e[a*5+2];
      c3 += v * s_e[a*5+3]; c4 += v * s_e[a*5+4];
    }
    int cc[5];
    cc[0] = min(max((int)(c0+0.5f),0),19); cc[1] = min(max((int)(c1+0.5f),0),19);
    cc[2] = min(max((int)(c2+0.5f),0),19); cc[3] = min(max((int)(c3+0.5f),0),19);
    cc[4] = min(max((int)(c4+0.5f),0),19);
    s_ssum[s] = ssum;
    _Float16* dst = Abuf + (row0 + s)*KC_ + 512;
#pragma unroll
    for (int t = 0; t < 16; ++t){
      half8 hv;
#pragma unroll
      for (int u = 0; u < 8; ++u){
        int k = t*8 + u;
        float v = 0.f;
        if (k < 100){ int f = k/20, l = k - f*20; v = (l <= cc[f]) ? 1.f : 0.f; }
        hv[u] = (_Float16)v;
      }
      *(half8*)(dst + t*8) = hv;
    }
  }
  half8 bf[8]; float lng[8], lnb[8];
#pragma unroll
  for (int t = 0; t < 8; ++t){
    int g = w*128 + t*16 + l15;
    bf[t] = *(const half8*)(s_mvfT + g*A_ + q*8);
    lng[t] = ln_g[g]; lnb[t] = ln_b[g];
  }
  __syncthreads();
  for (int gi = 0; gi < 8; ++gi){
    half8 af = *(const half8*)(s_sm + (gi*16 + l15)*A_ + q*8);
    floatx4 c[8];
#pragma unroll
    for (int t = 0; t < 8; ++t){
      floatx4 z = {0.f, 0.f, 0.f, 0.f};
      c[t] = __builtin_amdgcn_mfma_f32_16x16x32_f16(af, bf[t], z, 0, 0, 0);
    }
    float p1[4] = {0.f,0.f,0.f,0.f}, p2[4] = {0.f,0.f,0.f,0.f};
#pragma unroll
    for (int t = 0; t < 8; ++t)
#pragma unroll
      for (int r = 0; r < 4; ++r){ float v = c[t][r]; p1[r] += v; p2[r] += v*v; }
#pragma unroll
    for (int off = 1; off < 16; off <<= 1)
#pragma unroll
      for (int r = 0; r < 4; ++r){
        p1[r] += __shfl_xor(p1[r], off);
        p2[r] += __shfl_xor(p2[r], off);
      }
    int gb = gi & 1;
    if (l15 == 0){
#pragma unroll
      for (int r = 0; r < 4; ++r){ s_red1[gb][w][q*4+r] = p1[r]; s_red2[gb][w][q*4+r] = p2[r]; }
    }
    __syncthreads();
#pragma unroll
    for (int r = 0; r < 4; ++r){
      int sl = gi*16 + q*4 + r;
      int rr = q*4 + r;
      float t1 = s_red1[gb][0][rr] + s_red1[gb][1][rr] + s_red1[gb][2][rr] + s_red1[gb][3][rr];
      float t2 = s_red2[gb][0][rr] + s_red2[gb][1][rr] + s_red2[gb][2][rr] + s_red2[gb][3][rr];
      float inv = 1.f/(s_ssum[sl] + 1e-4f);
      float mu = t1*inv*(1.f/512.f);
      float var = t2*inv*inv*(1.f/512.f) - mu*mu;
      float rs = rsqrtf(var + 1e-5f);
      _Float16* orow = Abuf + (row0 + sl)*KC_;
#pragma unroll
      for (int t = 0; t < 8; ++t){
        float o = (c[t][r]*inv - mu)*rs*lng[t] + lnb[t];
        orow[w*128 + t*16 + l15] = (_Float16)o;
      }
    }
  }
}

// ================= K2: GRU fused GEMM, 1-barrier/tile BK=64 =================
// BM=256 rows, DN=64 d-cols, B-panel=192 Wcat rows (3 gates x 64), K=640 ->
// 10 tiles of BK=64; 48 MFMA + 22 ds_read per wave per tile, ONE
// __syncthreads per tile (its vmcnt(0) drains the stage issued one full tile
// (~2700 cyc) earlier — latency fully covered). Stage-1-ahead, 2 LDS buffers
// (write (T+1)&1, read T&1). XOR-chunk both-sides swizzle (R5/R6-proven,
// bank-conflict 0). Gate-2 target: acc[.][2] (h_n) tiles 0-7, acc[.][3]
// (i_n) tiles 8-9 — same accumulation order as R6 (bit-identical).
#define GSTG_A(T) do{ \
    __builtin_amdgcn_global_load_lds((gas_t)(qA0 + (T)*64),            (las_t)(&gmA[(T)&1][0] + wvid*1024),        16, 0, 0); \
    __builtin_amdgcn_global_load_lds((gas_t)(qA1 + (T)*64),            (las_t)(&gmA[(T)&1][0] + wvid*1024 + 512),  16, 0, 0); \
    __builtin_amdgcn_global_load_lds((gas_t)(qA0 + 128*KC_ + (T)*64),  (las_t)(&gmA[(T)&1][0] + 8192 + wvid*1024), 16, 0, 0); \
    __builtin_amdgcn_global_load_lds((gas_t)(qA1 + 128*KC_ + (T)*64),  (las_t)(&gmA[(T)&1][0] + 8192 + wvid*1024 + 512), 16, 0, 0); \
  }while(0)
#define GSTG_B(T) do{ \
    __builtin_amdgcn_global_load_lds((gas_t)(qB0 + (T)*64), (las_t)(&gmB[(T)&1][0] + wvid*1536),        16, 0, 0); \
    __builtin_amdgcn_global_load_lds((gas_t)(qB1 + (T)*64), (las_t)(&gmB[(T)&1][0] + wvid*1536 + 512),  16, 0, 0); \
    __builtin_amdgcn_global_load_lds((gas_t)(qB2 + (T)*64), (las_t)(&gmB[(T)&1][0] + wvid*1536 + 1024), 16, 0, 0); \
  }while(0)
#define GRD_A(DST, T, MF0) do{ \
    const _Float16* ba_ = &gmA[(T)&1][0]; \
    DST[0][0] = *(const half8*)(ba_ + aoff0 + (MF0)*1024); \
    DST[0][1] = *(const half8*)(ba_ + aoff1 + (MF0)*1024); \
    DST[1][0] = *(const half8*)(ba_ + aoff0 + ((MF0)+1)*1024); \
    DST[1][1] = *(const half8*)(ba_ + aoff1 + ((MF0)+1)*1024); \
  }while(0)
#define GRD_B(DST, T) do{ \
    const _Float16* bb_ = &gmB[(T)&1][0]; \
    _Pragma("unroll") \
    for (int g_ = 0; g_ < 3; ++g_){ \
      DST[g_][0] = *(const half8*)(bb_ + bo0[g_]); \
      DST[g_][1] = *(const half8*)(bb_ + bo1[g_]); \
    } \
  }while(0)
#define GMMQ(AV, BV, MF0, G2) do{ \
    _Pragma("unroll") \
    for (int u_ = 0; u_ < 2; ++u_){ \
      acc[(MF0)+u_][0]  = __builtin_amdgcn_mfma_f32_16x16x32_f16(AV[u_][0], BV[0][0], acc[(MF0)+u_][0], 0, 0, 0); \
      acc[(MF0)+u_][0]  = __builtin_amdgcn_mfma_f32_16x16x32_f16(AV[u_][1], BV[0][1], acc[(MF0)+u_][0], 0, 0, 0); \
      acc[(MF0)+u_][1]  = __builtin_amdgcn_mfma_f32_16x16x32_f16(AV[u_][0], BV[1][0], acc[(MF0)+u_][1], 0, 0, 0); \
      acc[(MF0)+u_][1]  = __builtin_amdgcn_mfma_f32_16x16x32_f16(AV[u_][1], BV[1][1], acc[(MF0)+u_][1], 0, 0, 0); \
      acc[(MF0)+u_][G2] = __builtin_amdgcn_mfma_f32_16x16x32_f16(AV[u_][0], BV[2][0], acc[(MF0)+u_][G2], 0, 0, 0); \
      acc[(MF0)+u_][G2] = __builtin_amdgcn_mfma_f32_16x16x32_f16(AV[u_][1], BV[2][1], acc[(MF0)+u_][G2], 0, 0, 0); \
    } \
  }while(0)
#define GTILE3(T, G2) do{ \
    __syncthreads(); \
    if ((T) < 9){ GSTG_A((T)+1); GSTG_B((T)+1); } \
    GRD_B(bA, T); \
    GRD_A(a_e, T, 0); GMMQ(a_e, bA, 0, G2); \
    GRD_A(a_o, T, 2); GMMQ(a_o, bA, 2, G2); \
    GRD_A(a_e, T, 4); GMMQ(a_e, bA, 4, G2); \
    GRD_A(a_o, T, 6); GMMQ(a_o, bA, 6, G2); \
  }while(0)

__global__ __launch_bounds__(512, 2) void k_gru8(
    const _Float16* __restrict__ Abuf, const _Float16* __restrict__ Wcat,
    const float* __restrict__ bih, const float* __restrict__ bhh,
    _Float16* __restrict__ H){
  __shared__ _Float16 gmA[2][SMH];      // 64 KB
  __shared__ _Float16 gmB[2][192*64];   // 48 KB
  int tid = threadIdx.x;
  int lane = tid & 63, wvid = tid >> 6;
  int wm = wvid & 1, wn = wvid >> 1;
  int q = lane >> 4, l15 = lane & 15;
  int x_ = l15 & 7;
  int bid = blockIdx.x;
  // XCD swizzle: bid[2:0]=xcd, bid[5:3]=dt (inner: B panels L2-hot), bid[10:6]=mtl
  int mt = (bid & 7)*32 + (bid >> 6);
  int dt = (bid >> 3) & 7;
  int m0 = mt*256, d0 = dt*64;
  int swzlo = (q ^ (x_ & 3))*8;
  int aoff0 = (wm*128 + l15)*64 + ((0 ^ (x_>>2))*4)*8 + swzlo;
  int aoff1 = (wm*128 + l15)*64 + ((1 ^ (x_>>2))*4)*8 + swzlo;
  int bo0[3], bo1[3];
#pragma unroll
  for (int g = 0; g < 3; ++g){
    int rb = (g*64 + wn*16 + l15)*64;
    bo0[g] = rb + ((0 ^ (x_>>2))*4)*8 + swzlo;
    bo1[g] = rb + ((1 ^ (x_>>2))*4)*8 + swzlo;
  }
  int srow = wvid*16 + (lane >> 3);
  int sc = ((lane & 7) ^ ((lane >> 3) & 7))*8;
  const _Float16* qA0 = Abuf + (size_t)(m0 + srow)*KC_ + sc;
  const _Float16* qA1 = Abuf + (size_t)(m0 + srow + 8)*KC_ + sc;
  int rb0 = wvid*24 + (lane >> 3);
  const _Float16* qB0 = Wcat + (size_t)(((rb0    )>>6)*512 + d0 + ((rb0    )&63))*KC_ + sc;
  const _Float16* qB1 = Wcat + (size_t)(((rb0+ 8)>>6)*512 + d0 + ((rb0+ 8)&63))*KC_ + sc;
  const _Float16* qB2 = Wcat + (size_t)(((rb0+16)>>6)*512 + d0 + ((rb0+16)&63))*KC_ + sc;
  floatx4 acc[8][4] = {};
  half8 a_e[2][2], a_o[2][2], bA[3][2];
  GSTG_A(0); GSTG_B(0);
  GTILE3(0, 2); GTILE3(1, 2);
  GTILE3(2, 2); GTILE3(3, 2);
  GTILE3(4, 2); GTILE3(5, 2);
  GTILE3(6, 2); GTILE3(7, 2);
  GTILE3(8, 3); GTILE3(9, 3);
  int d = d0 + wn*16 + l15;
  float br  = bih[d] + bhh[d];
  float bz  = bih[512+d] + bhh[512+d];
  float bnh = bhh[1024+d];
  float bni = bih[1024+d];
#pragma unroll
  for (int mf = 0; mf < 8; ++mf){
#pragma unroll
    for (int r = 0; r < 4; ++r){
      int m = m0 + wm*128 + mf*16 + q*4 + r;
      float gr  = acc[mf][0][r] + br;
      float gz  = acc[mf][1][r] + bz;
      float hn  = acc[mf][2][r] + bnh;
      float in_ = acc[mf][3][r] + bni;
      float rrv = sigmoidf_(gr);
      float zz  = sigmoidf_(gz);
      float nn  = tanhf_(in_ + rrv*hn);
      float hp  = (float)Abuf[(size_t)m*KC_ + d];
      H[(size_t)m*G_ + d] = (_Float16)((1.f-zz)*nn + zz*hp);
    }
  }
}

// ======================= 8-phase 256x256 FF GEMM ============================
// (R5-proven) BM=BN=256, BK=64, 8 waves (2M x 4N), per-wave 128x64 out.
#define STG_A8(T) do{ \
    __builtin_amdgcn_global_load_lds((gas_t)(pA0 + (T)*64),           (las_t)(&smA8[(T)&1][0] + wvid*1024),        16, 0, 0); \
    __builtin_amdgcn_global_load_lds((gas_t)(pA1 + (T)*64),           (las_t)(&smA8[(T)&1][0] + wvid*1024 + 512),  16, 0, 0); \
    __builtin_amdgcn_global_load_lds((gas_t)(pA0 + 128*G_ + (T)*64),  (las_t)(&smA8[(T)&1][0] + 8192 + wvid*1024), 16, 0, 0); \
    __builtin_amdgcn_global_load_lds((gas_t)(pA1 + 128*G_ + (T)*64),  (las_t)(&smA8[(T)&1][0] + 8192 + wvid*1024 + 512), 16, 0, 0); \
  }while(0)
#define STG_B8(T,H) do{ \
    __builtin_amdgcn_global_load_lds((gas_t)(pB0 + (H)*128*G_ + (T)*64), (las_t)(&smB8[(T)&1][0] + (H)*8192 + wvid*1024),       16, 0, 0); \
    __builtin_amdgcn_global_load_lds((gas_t)(pB1 + (H)*128*G_ + (T)*64), (las_t)(&smB8[(T)&1][0] + (H)*8192 + wvid*1024 + 512), 16, 0, 0); \
  }while(0)
#define RD_A8(DST, T, MF0) do{ \
    const _Float16* ba_ = &smA8[(T)&1][0]; \
    DST[0][0] = *(const half8*)(ba_ + aoff0 + (MF0)*1024); \
    DST[0][1] = *(const half8*)(ba_ + aoff1 + (MF0)*1024); \
    DST[1][0] = *(const half8*)(ba_ + aoff0 + ((MF0)+1)*1024); \
    DST[1][1] = *(const half8*)(ba_ + aoff1 + ((MF0)+1)*1024); \
  }while(0)
#define RD_B8(DST, T) do{ \
    const _Float16* bb_ = &smB8[(T)&1][0]; \
    _Pragma("unroll") \
    for (int nf_ = 0; nf_ < 4; ++nf_){ \
      DST[nf_][0] = *(const half8*)(bb_ + boff0 + nf_*1024); \
      DST[nf_][1] = *(const half8*)(bb_ + boff1 + nf_*1024); \
    } \
  }while(0)
#define MMQ8(AV, BV, MF0) do{ \
    _Pragma("unroll") \
    for (int u_ = 0; u_ < 2; ++u_) \
    _Pragma("unroll") \
    for (int nf_ = 0; nf_ < 4; ++nf_){ \
      acc[(MF0)+u_][nf_] = __builtin_amdgcn_mfma_f32_16x16x32_f16(AV[u_][0], BV[nf_][0], acc[(MF0)+u_][nf_], 0, 0, 0); \
      acc[(MF0)+u_][nf_] = __builtin_amdgcn_mfma_f32_16x16x32_f16(AV[u_][1], BV[nf_][1], acc[(MF0)+u_][nf_], 0, 0, 0); \
    } \
  }while(0)
#define PH_Q0(T, BC) do{ if ((T)+1 <= 7) STG_A8((T)+1); RD_A8(a_o, T, 2); \
    __builtin_amdgcn_s_barrier(); __builtin_amdgcn_s_setprio(1); MMQ8(a_e, BC, 0); \
    __builtin_amdgcn_s_setprio(0); __builtin_amdgcn_s_barrier(); }while(0)
#define PH_Q1(T, BC) do{ if ((T)+2 <= 7) STG_B8((T)+2, 0); RD_A8(a_e, T, 4); \
    __builtin_amdgcn_s_barrier(); __builtin_amdgcn_s_setprio(1); MMQ8(a_o, BC, 2); \
    __builtin_amdgcn_s_setprio(0); __builtin_amdgcn_s_barrier(); }while(0)
#define PH_Q2(T, BC) do{ if ((T)+2 <= 7) STG_B8((T)+2, 1); RD_A8(a_o, T, 6); \
    __builtin_amdgcn_s_barrier(); __builtin_amdgcn_s_setprio(1); MMQ8(a_e, BC, 4); \
    __builtin_amdgcn_s_setprio(0); __builtin_amdgcn_s_barrier(); }while(0)
#define PH_Q3(T, BC, BN) do{ \
    if ((T) < 7){ \
      if ((T) < 6) asm volatile("s_waitcnt vmcnt(4)" ::: "memory"); \
      else         asm volatile("s_waitcnt vmcnt(0)" ::: "memory"); \
      RD_B8(BN, (T)+1); RD_A8(a_e, (T)+1, 0); \
    } \
    __builtin_amdgcn_s_barrier(); __builtin_amdgcn_s_setprio(1); MMQ8(a_o, BC, 6); \
    __builtin_amdgcn_s_setprio(0); __builtin_amdgcn_s_barrier(); }while(0)
#define TILE8(T, BC, BN) do{ PH_Q0(T, BC); PH_Q1(T, BC); PH_Q2(T, BC); PH_Q3(T, BC, BN); }while(0)

#define K8_SETUP(Amat, Wmat) \
  int tid = threadIdx.x; \
  int lane = tid & 63, wvid = tid >> 6; \
  int wm = wvid & 1, wn = wvid >> 1; \
  int q = lane >> 4, l15 = lane & 15; \
  int x_ = l15 & 7; \
  int bid = blockIdx.x; \
  int wg = (bid & 7)*64 + (bid >> 3); \
  int mt = wg >> 1, nt = wg & 1; \
  int m0 = mt*256, n0 = nt*256; \
  int swzlo = (q ^ (x_ & 3))*8; \
  int aoff0 = (wm*128 + l15)*64 + ((0 ^ (x_>>2))*4)*8 + swzlo; \
  int aoff1 = (wm*128 + l15)*64 + ((1 ^ (x_>>2))*4)*8 + swzlo; \
  int boff0 = (wn*64 + l15)*64 + ((0 ^ (x_>>2))*4)*8 + swzlo; \
  int boff1 = (wn*64 + l15)*64 + ((1 ^ (x_>>2))*4)*8 + swzlo; \
  int srow = wvid*16 + (lane >> 3); \
  int sc = ((lane & 7) ^ ((lane >> 3) & 7))*8; \
  const _Float16* pA0 = Amat + (size_t)(m0 + srow)*G_ + sc; \
  const _Float16* pA1 = Amat + (size_t)(m0 + srow + 8)*G_ + sc; \
  const _Float16* pB0 = Wmat + (size_t)(n0 + srow)*G_ + sc; \
  const _Float16* pB1 = Wmat + (size_t)(n0 + srow + 8)*G_ + sc; \
  floatx4 acc[8][4] = {}; \
  half8 a_e[2][2], a_o[2][2], bA[4][2], bB[4][2]; \
  STG_A8(0); STG_B8(0,0); STG_B8(0,1); STG_B8(1,0); STG_B8(1,1); \
  asm volatile("s_waitcnt vmcnt(4)" ::: "memory"); \
  __builtin_amdgcn_s_barrier(); \
  RD_B8(bA, 0); RD_A8(a_e, 0, 0); \
  TILE8(0, bA, bB); TILE8(1, bB, bA); \
  TILE8(2, bA, bB); TILE8(3, bB, bA); \
  TILE8(4, bA, bB); TILE8(5, bB, bA); \
  TILE8(6, bA, bB); TILE8(7, bB, bA);

// ---------------- K3: FF GEMM 8-phase  Out = relu(A@W^T+b) ------------------
__global__ __launch_bounds__(512, 2) void k_gemm8(
    const _Float16* __restrict__ A, const _Float16* __restrict__ W,
    const float* __restrict__ bias, _Float16* __restrict__ Out){
  __shared__ _Float16 smA8[2][SMH];   // 64 KB
  __shared__ _Float16 smB8[2][SMH];   // 64 KB
  K8_SETUP(A, W)
  float bv[4];
#pragma unroll
  for (int nf = 0; nf < 4; ++nf) bv[nf] = bias[n0 + wn*64 + nf*16 + l15];
#pragma unroll
  for (int mf = 0; mf < 8; ++mf){
    int m = m0 + wm*128 + mf*16 + q*4;
#pragma unroll
    for (int nf = 0; nf < 4; ++nf){
      int n = n0 + wn*64 + nf*16 + l15;
#pragma unroll
      for (int r = 0; r < 4; ++r)
        Out[(size_t)(m+r)*G_ + n] = (_Float16)fmaxf(acc[mf][nf][r] + bv[nf], 0.f);
    }
  }
}

// ---------------- K3b: FF3 8-phase GEMM + LN/score partials -----------------
__global__ __launch_bounds__(512, 2) void k_ff38(
    const _Float16* __restrict__ A, const _Float16* __restrict__ W,
    const float* __restrict__ bias, const float* __restrict__ ln_pre_g,
    const float* __restrict__ Ws, float* __restrict__ Pbuf){
  __shared__ _Float16 smA8[2][SMH];
  __shared__ _Float16 smB8[2][SMH];
  K8_SETUP(A, W)
  float gws[4], bv[4];
#pragma unroll
  for (int nf = 0; nf < 4; ++nf){
    int n = n0 + wn*64 + nf*16 + l15;
    gws[nf] = ln_pre_g[n]*Ws[n];
    bv[nf] = bias[n];
  }
  float* sP = (float*)&smB8[0][0];   // reuse: [256 rows][4 wn][3], 12 KB
#pragma unroll
  for (int mf = 0; mf < 8; ++mf){
#pragma unroll
    for (int r = 0; r < 4; ++r){
      float p1 = 0.f, p2 = 0.f, p3 = 0.f;
#pragma unroll
      for (int nf = 0; nf < 4; ++nf){
        float xv = fmaxf(acc[mf][nf][r] + bv[nf], 0.f);
        p1 += xv; p2 += xv*xv; p3 += gws[nf]*xv;
      }
#pragma unroll
      for (int off = 1; off < 16; off <<= 1){
        p1 += __shfl_xor(p1, off);
        p2 += __shfl_xor(p2, off);
        p3 += __shfl_xor(p3, off);
      }
      if (l15 == 0){
        int rl = wm*128 + mf*16 + q*4 + r;
        sP[(rl*4 + wn)*3 + 0] = p1;
        sP[(rl*4 + wn)*3 + 1] = p2;
        sP[(rl*4 + wn)*3 + 2] = p3;
      }
    }
  }
  __syncthreads();
  if (tid < 256){
    int m = m0 + tid;
    float* dst = Pbuf + ((size_t)m*2 + nt)*3;
#pragma unroll
    for (int c = 0; c < 3; ++c)
      dst[c] = sP[(tid*4+0)*3+c] + sP[(tid*4+1)*3+c] +
               sP[(tid*4+2)*3+c] + sP[(tid*4+3)*3+c];
  }
}

// ---------------- K4: finish scores from partials + zero spect --------------
__global__ __launch_bounds__(256) void k_score_fin(
    const float* __restrict__ Pbuf, const float* __restrict__ g,
    const float* __restrict__ bta, const float* __restrict__ Ws,
    const float* __restrict__ bs, float* __restrict__ scores,
    float* __restrict__ spect){
  __shared__ float red[8];
  int tid = threadIdx.x, lane = tid & 63, wv = tid >> 6;
  if (blockIdx.x < 32) spect[(size_t)blockIdx.x*256 + tid] = 0.f;
  int i0 = tid*2;
  float c1p = g[i0]*Ws[i0] + g[i0+1]*Ws[i0+1];
  float c2p = bta[i0]*Ws[i0] + bta[i0+1]*Ws[i0+1];
  c1p = wave_sum_f(c1p); c2p = wave_sum_f(c2p);
  if (lane == 0){ red[wv] = c1p; red[4+wv] = c2p; }
  __syncthreads();
  float c1 = red[0]+red[1]+red[2]+red[3];
  float c2 = red[4]+red[5]+red[6]+red[7] + bs[0];
  size_t row = (size_t)blockIdx.x*256 + tid;
  const float* p = Pbuf + row*6;
  float2 u0 = *(const float2*)p;
  float2 u1 = *(const float2*)(p+2);
  float2 u2 = *(const float2*)(p+4);
  float P1 = u0.x + u1.y;
  float P2 = u0.y + u2.x;
  float P3 = u1.x + u2.y;
  float mu = P1*(1.f/512.f);
  float var = P2*(1.f/512.f) - mu*mu;
  float rs = rsqrtf(var + 1e-5f);
  scores[row] = rs*(P3 - mu*c1) + c2;
}

// ---------------- K5: softmax over S per batch ------------------------------
__global__ __launch_bounds__(256) void k_softmax(
    const float* __restrict__ scores, float* __restrict__ probs){
  __shared__ float red[4];
  int b = blockIdx.x, tid = threadIdx.x, lane = tid & 63, wv = tid >> 6;
  const float* sp = scores + (size_t)b*S_;
  float* pp = probs + (size_t)b*S_;
  float mx = -1e30f;
  for (int i = tid; i < S_; i += 256) mx = fmaxf(mx, sp[i]);
  mx = wave_max_f(mx);
  if (lane == 0) red[wv] = mx;
  __syncthreads();
  mx = fmaxf(fmaxf(red[0], red[1]), fmaxf(red[2], red[3]));
  __syncthreads();
  float sum = 0.f;
  for (int i = tid; i < S_; i += 256){
    float e = __expf(sp[i]-mx);
    pp[i] = e;
    sum += e;
  }
  sum = wave_sum_f(sum);
  if (lane == 0) red[wv] = sum;
  __syncthreads();
  sum = red[0]+red[1]+red[2]+red[3];
  float inv = 1.f/sum;
  for (int i = tid; i < S_; i += 256)
    pp[i] *= inv;
}

// ---------------- K6: spectrum scatter (parallelized 8x) --------------------
__global__ __launch_bounds__(256) void k_spect_p(
    const float* __restrict__ peaks, const float* __restrict__ probs,
    float* __restrict__ spect){
  __shared__ float bins[512];
  int b = blockIdx.x, chunk = blockIdx.y, tid = threadIdx.x;
  bins[tid] = 0.f; bins[tid+256] = 0.f;
  __syncthreads();
  int s0 = chunk*(S_/8);
  for (int i = tid; i < (S_/8)*M_; i += 256){
    int s = s0 + (i >> 3), m = i & 7;
    const float* pk = peaks + (((size_t)b*S_ + s)*M_ + m)*2;
    float mass = pk[0], inten = pk[1];
    float p = probs[(size_t)b*S_ + s];
    int bin = (int)rintf(mass);
    bin = min(max(bin, 0), 511);
    atomicAdd(&bins[bin], inten*p);
  }
  __syncthreads();
  atomicAdd(&spect[(size_t)b*512 + tid],       bins[tid]);
  atomicAdd(&spect[(size_t)b*512 + tid + 256], bins[tid+256]);
}

// ---------------- launcher --------------------------------------------------
extern "C" void kernel_launch(void* const* d_in, const int* in_sizes, int n_in,
                              void* d_out, int out_size, void* d_ws, size_t ws_size,
                              hipStream_t stream) {
  const float* vf       = (const float*)d_in[0];
  const float* mask     = (const float*)d_in[1];
  const float* eoh      = (const float*)d_in[2];
  const float* subs     = (const float*)d_in[4];
  const float* peaks    = (const float*)d_in[5];
  const float* ln_sub_g = (const float*)d_in[6];
  const float* ln_sub_b = (const float*)d_in[7];
  const float* W_ih     = (const float*)d_in[8];
  const float* W_hh     = (const float*)d_in[9];
  const float* b_ih     = (const float*)d_in[10];
  const float* b_hh     = (const float*)d_in[11];
  const float* W1       = (const float*)d_in[12];
  const float* b1       = (const float*)d_in[13];
  const float* W2a      = (const float*)d_in[14];
  const float* b2a      = (const float*)d_in[15];
  const float* W2b      = (const float*)d_in[16];
  const float* b2b      = (const float*)d_in[17];
  const float* ln_pre_g = (const float*)d_in[18];
  const float* ln_pre_b = (const float*)d_in[19];
  const float* Ws       = (const float*)d_in[20];
  const float* bs       = (const float*)d_in[21];
  float* out = (float*)d_out;            // [0,8192) spect, [8192,73728) probs
  float* probs_out = out + (size_t)B_*512;

  // workspace carve — ~158 MB (ws >= ~206 MB proven)
  char* w = (char*)d_ws;
  float* scores = (float*)w;     w += (size_t)BS_*4;
  float* Pbuf   = (float*)w;     w += (size_t)BS_*12*4;        // 3 MB (uses 6/row)
  _Float16* Wcat = (_Float16*)w; w += (size_t)NG_*KC_*2;       // ~2 MB
  _Float16* W1h  = (_Float16*)w; w += (size_t)G_*G_*2;
  _Float16* W2ah = (_Float16*)w; w += (size_t)G_*G_*2;
  _Float16* W2bh = (_Float16*)w; w += (size_t)G_*G_*2;
  _Float16* Abuf = (_Float16*)w; w += (size_t)BS_*KC_*2;       // 84 MB
  _Float16* bufh0 = (_Float16*)w;                              // 67 MB (H)
  _Float16* bufh1 = Abuf;        // x1 reuses A region (84 >= 67 MB)

  k_cvt3<<<dim3((G_*G_/4+255)/256, 3), 256, 0, stream>>>(W1, W2a, W2b, W1h);
  k_buildw<<<NG_, 64, 0, stream>>>(W_hh, W_ih, Wcat);
  k_prep_mfma<<<dim3(S_/128, B_), 256, 0, stream>>>(vf, mask, eoh, subs,
                                                    ln_sub_g, ln_sub_b, Abuf);
  k_gru8<<<2048, 512, 0, stream>>>(Abuf, Wcat, b_ih, b_hh, bufh0);
  k_gemm8<<<512, 512, 0, stream>>>(bufh0, W1h,  b1,  bufh1);   // x1
  k_gemm8<<<512, 512, 0, stream>>>(bufh1, W2ah, b2a, bufh0);   // x2
  k_ff38<<<512, 512, 0, stream>>>(bufh0, W2bh, b2b, ln_pre_g, Ws, Pbuf);
  k_score_fin<<<BS_/256, 256, 0, stream>>>(Pbuf, ln_pre_g, ln_pre_b, Ws, bs,
                                           scores, out);
  k_softmax<<<B_, 256, 0, stream>>>(scores, probs_out);
  k_spect_p<<<dim3(B_, 8), 256, 0, stream>>>(peaks, probs_out, out);
}

// Round 8
// 466.253 us; speedup vs baseline: 1.0384x; 1.0384x over previous
//
#include <hip/hip_runtime.h>
#include <math.h>

#define B_ 16
#define A_ 32
#define G_ 512
#define S_ 4096
#define M_ 8
#define BS_ 65536
#define KC_ 640      // concat K: 512 normed + 100 OH + 28 pad
#define NG_ 1536
#define SMH 16384    // halfs per LDS buffer per matrix (256 rows x 64 halfs)

typedef _Float16 half8 __attribute__((ext_vector_type(8)));
typedef _Float16 half4v __attribute__((ext_vector_type(4)));
typedef _Float16 half2v __attribute__((ext_vector_type(2)));
typedef float floatx4 __attribute__((ext_vector_type(4)));

typedef const __attribute__((address_space(1))) void* gas_t;
typedef __attribute__((address_space(3))) void* las_t;

// ---------------- helpers ----------------
__device__ __forceinline__ float wave_sum_f(float v){
#pragma unroll
  for (int o = 32; o > 0; o >>= 1) v += __shfl_xor(v, o);
  return v;
}
__device__ __forceinline__ float wave_max_f(float v){
#pragma unroll
  for (int o = 32; o > 0; o >>= 1) v = fmaxf(v, __shfl_xor(v, o));
  return v;
}
__device__ __forceinline__ float sigmoidf_(float x){ return 1.f/(1.f+__expf(-x)); }
__device__ __forceinline__ float tanhf_(float x){ return 1.f - 2.f/(__expf(2.f*x)+1.f); }

// ---------------- K0: fp32 -> fp16 convert (3 G*G) + Wcat build -------------
// grid (256, 4): y in {0,1,2} converts matrix y into d; y==3 builds
// Wcat[1536][640] = [W_hh | W_ih | 0] (6 rows per block).
__global__ __launch_bounds__(256) void k_cvtw(const float* __restrict__ s0,
                                              const float* __restrict__ s1,
                                              const float* __restrict__ s2,
                                              _Float16* __restrict__ d,
                                              const float* __restrict__ Whh,
                                              const float* __restrict__ Wih,
                                              _Float16* __restrict__ Wcat){
  if (blockIdx.y == 3){
    int j0 = blockIdx.x*6;
    for (int j = j0; j < j0+6; ++j)
      for (int p = threadIdx.x; p < KC_; p += 256){
        float v = 0.f;
        if (p < 512) v = Whh[(size_t)j*512 + p];
        else if (p < 612) v = Wih[(size_t)j*100 + (p - 512)];
        Wcat[(size_t)j*KC_ + p] = (_Float16)v;
      }
    return;
  }
  const float* s = (blockIdx.y == 0) ? s0 : (blockIdx.y == 1) ? s1 : s2;
  int i = (blockIdx.x*256 + threadIdx.x)*4;
  if (i >= G_*G_) return;
  float4 v = *(const float4*)(s+i);
  half4v o; o[0]=(_Float16)v.x; o[1]=(_Float16)v.y; o[2]=(_Float16)v.z; o[3]=(_Float16)v.w;
  *(half4v*)(d + (size_t)blockIdx.y*G_*G_ + i) = o;
}

// ---------------- K1: MFMA prep — swvs GEMM + LN + counts + OH --------------
__global__ __launch_bounds__(256) void k_prep_mfma(
    const float* __restrict__ vf, const float* __restrict__ mask,
    const float* __restrict__ eoh, const float* __restrict__ subs,
    const float* __restrict__ ln_g, const float* __restrict__ ln_b,
    _Float16* __restrict__ Abuf){
  __shared__ _Float16 s_mvfT[G_*A_];   // [g][a], masked vf, 32 KB
  __shared__ _Float16 s_sm[128*A_];    // [s][a], raw subs, 8 KB
  __shared__ float s_m[A_];
  __shared__ float s_e[A_*5];
  __shared__ float s_ssum[128];
  __shared__ float s_red1[2][4][16];
  __shared__ float s_red2[2][4][16];
  int tid = threadIdx.x;
  int bx = blockIdx.x, b = blockIdx.y;
  int lane = tid & 63, w = tid >> 6;
  int q = lane >> 4, l15 = lane & 15;
  size_t row0 = (size_t)b*S_ + (size_t)bx*128;
  if (tid < A_)   s_m[tid] = mask[b*A_ + tid];
  if (tid < A_*5) s_e[tid] = eoh[b*A_*5 + tid];
  __syncthreads();
  {
    int p = tid & 15, gseg = tid >> 4;
    float mk0 = s_m[2*p], mk1 = s_m[2*p+1];
    const float* v0 = vf + ((size_t)b*A_ + 2*p)*G_ + gseg*32;
    const float* v1 = v0 + G_;
#pragma unroll
    for (int i = 0; i < 32; i += 4){
      float4 a = *(const float4*)(v0 + i);
      float4 c = *(const float4*)(v1 + i);
      float av[4] = {a.x, a.y, a.z, a.w};
      float cv[4] = {c.x, c.y, c.z, c.w};
#pragma unroll
      for (int j = 0; j < 4; ++j){
        half2v h; h[0] = (_Float16)(av[j]*mk0); h[1] = (_Float16)(cv[j]*mk1);
        *(half2v*)(s_mvfT + (gseg*32 + i + j)*A_ + 2*p) = h;
      }
    }
  }
  {
    int s = tid >> 1, hh = tid & 1;
    const float* sp = subs + (row0 + s)*A_ + hh*16;
    _Float16* dst = s_sm + s*A_ + hh*16;
#pragma unroll
    for (int i = 0; i < 16; i += 4){
      float4 v = *(const float4*)(sp + i);
      half4v h; h[0]=(_Float16)v.x; h[1]=(_Float16)v.y; h[2]=(_Float16)v.z; h[3]=(_Float16)v.w;
      *(half4v*)(dst + i) = h;
    }
  }
  __syncthreads();
  if (tid < 128){
    int s = tid;
    float ssum = 0.f, c0=0.f, c1=0.f, c2=0.f, c3=0.f, c4=0.f;
#pragma unroll
    for (int a = 0; a < A_; ++a){
      float v = (float)s_sm[s*A_ + a];
      ssum += v * s_m[a];
      c0 += v * s_e[a*5+0]; c1 += v * s_e[a*5+1]; c2 += v * s_e[a*5+2];
      c3 += v * s_e[a*5+3]; c4 += v * s_e[a*5+4];
    }
    int cc[5];
    cc[0] = min(max((int)(c0+0.5f),0),19); cc[1] = min(max((int)(c1+0.5f),0),19);
    cc[2] = min(max((int)(c2+0.5f),0),19); cc[3] = min(max((int)(c3+0.5f),0),19);
    cc[4] = min(max((int)(c4+0.5f),0),19);
    s_ssum[s] = ssum;
    _Float16* dst = Abuf + (row0 + s)*KC_ + 512;
#pragma unroll
    for (int t = 0; t < 16; ++t){
      half8 hv;
#pragma unroll
      for (int u = 0; u < 8; ++u){
        int k = t*8 + u;
        float v = 0.f;
        if (k < 100){ int f = k/20, l = k - f*20; v = (l <= cc[f]) ? 1.f : 0.f; }
        hv[u] = (_Float16)v;
      }
      *(half8*)(dst + t*8) = hv;
    }
  }
  half8 bf[8]; float lng[8], lnb[8];
#pragma unroll
  for (int t = 0; t < 8; ++t){
    int g = w*128 + t*16 + l15;
    bf[t] = *(const half8*)(s_mvfT + g*A_ + q*8);
    lng[t] = ln_g[g]; lnb[t] = ln_b[g];
  }
  __syncthreads();
  for (int gi = 0; gi < 8; ++gi){
    half8 af = *(const half8*)(s_sm + (gi*16 + l15)*A_ + q*8);
    floatx4 c[8];
#pragma unroll
    for (int t = 0; t < 8; ++t){
      floatx4 z = {0.f, 0.f, 0.f, 0.f};
      c[t] = __builtin_amdgcn_mfma_f32_16x16x32_f16(af, bf[t], z, 0, 0, 0);
    }
    float p1[4] = {0.f,0.f,0.f,0.f}, p2[4] = {0.f,0.f,0.f,0.f};
#pragma unroll
    for (int t = 0; t < 8; ++t)
#pragma unroll
      for (int r = 0; r < 4; ++r){ float v = c[t][r]; p1[r] += v; p2[r] += v*v; }
#pragma unroll
    for (int off = 1; off < 16; off <<= 1)
#pragma unroll
      for (int r = 0; r < 4; ++r){
        p1[r] += __shfl_xor(p1[r], off);
        p2[r] += __shfl_xor(p2[r], off);
      }
    int gb = gi & 1;
    if (l15 == 0){
#pragma unroll
      for (int r = 0; r < 4; ++r){ s_red1[gb][w][q*4+r] = p1[r]; s_red2[gb][w][q*4+r] = p2[r]; }
    }
    __syncthreads();
#pragma unroll
    for (int r = 0; r < 4; ++r){
      int sl = gi*16 + q*4 + r;
      int rr = q*4 + r;
      float t1 = s_red1[gb][0][rr] + s_red1[gb][1][rr] + s_red1[gb][2][rr] + s_red1[gb][3][rr];
      float t2 = s_red2[gb][0][rr] + s_red2[gb][1][rr] + s_red2[gb][2][rr] + s_red2[gb][3][rr];
      float inv = 1.f/(s_ssum[sl] + 1e-4f);
      float mu = t1*inv*(1.f/512.f);
      float var = t2*inv*inv*(1.f/512.f) - mu*mu;
      float rs = rsqrtf(var + 1e-5f);
      _Float16* orow = Abuf + (row0 + sl)*KC_;
#pragma unroll
      for (int t = 0; t < 8; ++t){
        float o = (c[t][r]*inv - mu)*rs*lng[t] + lnb[t];
        orow[w*128 + t*16 + l15] = (_Float16)o;
      }
    }
  }
}

// ---------------- K2: fused (gh+gi) GEMM (3 gates) + GRU elementwise --------
// 2-phase double-buffered pipeline (R1-proven, best of 3 measured schedules:
// 197.5 vs 203.3 (8-phase) vs 209.7 (1-barrier/tile)): stage tile t+1 while
// computing tile t; one vmcnt(0)+s_barrier per K-step. 40 KB LDS -> 4 blk/CU.
__global__ __launch_bounds__(512) void k_gru_fused(
    const _Float16* __restrict__ Abuf, const _Float16* __restrict__ Wcat,
    const float* __restrict__ bih, const float* __restrict__ bhh,
    _Float16* __restrict__ H){
  __shared__ _Float16 smA[2][128*32];   // 16 KB
  __shared__ _Float16 smB[2][192*32];   // 24 KB
  int tid = threadIdx.x;
  int lane = tid & 63, wvid = tid >> 6;      // 8 waves
  int wm = wvid & 1, wn = wvid >> 1;
  int q = lane >> 4, l15 = lane & 15;
  int mt = blockIdx.x*64 + (blockIdx.y >> 3);
  int dt = blockIdx.y & 7;
  int m0 = mt*128, n0 = dt*64;
  floatx4 acc[3][4] = {};
  floatx4 accNI[4] = {};
  int offA[4], offB[3];
#pragma unroll
  for (int i = 0; i < 4; ++i){
    int r = wm*64 + i*16 + l15;
    offA[i] = (r*4 + (q ^ ((r>>2)&3)))*8;
  }
#pragma unroll
  for (int g = 0; g < 3; ++g){
    int rb = g*64 + wn*16 + l15;
    offB[g] = (rb*4 + (q ^ ((rb>>2)&3)))*8;
  }
  const _Float16* gA;
  {
    int u = wvid*64 + lane;
    int r = u >> 2, c = (u & 3) ^ ((r >> 2) & 3);
    gA = Abuf + (size_t)(m0 + r)*KC_ + c*8;
  }
  const _Float16* gB0;
  {
    int u = wvid*64 + lane;
    int rb = u >> 2, c = (u & 3) ^ ((rb >> 2) & 3);
    int grow = (rb >> 6)*512 + n0 + (rb & 63);
    gB0 = Wcat + (size_t)grow*KC_ + c*8;
  }
  const _Float16* gB1 = nullptr;
  if (wvid < 4){
    int u = (8 + wvid)*64 + lane;
    int rb = u >> 2, c = (u & 3) ^ ((rb >> 2) & 3);
    int grow = (rb >> 6)*512 + n0 + (rb & 63);
    gB1 = Wcat + (size_t)grow*KC_ + c*8;
  }
  // prologue: stage tile 0 into buf 0
  __builtin_amdgcn_global_load_lds((gas_t)gA,  (las_t)(smA[0] + wvid*512), 16, 0, 0);
  __builtin_amdgcn_global_load_lds((gas_t)gB0, (las_t)(smB[0] + wvid*512), 16, 0, 0);
  if (wvid < 4)
    __builtin_amdgcn_global_load_lds((gas_t)gB1, (las_t)(smB[0] + (8+wvid)*512), 16, 0, 0);
  asm volatile("s_waitcnt vmcnt(0)");
  __builtin_amdgcn_s_barrier();
  const int NT = KC_/32;   // 20 (tail phase from t=16)
  for (int t = 0; t < NT; ++t){
    int cur = t & 1;
    if (t + 1 < NT){
      int kc = (t+1)*32;
      __builtin_amdgcn_global_load_lds((gas_t)(gA + kc),  (las_t)(smA[cur^1] + wvid*512), 16, 0, 0);
      __builtin_amdgcn_global_load_lds((gas_t)(gB0 + kc), (las_t)(smB[cur^1] + wvid*512), 16, 0, 0);
      if (wvid < 4)
        __builtin_amdgcn_global_load_lds((gas_t)(gB1 + kc), (las_t)(smB[cur^1] + (8+wvid)*512), 16, 0, 0);
    }
    half8 af[4], bfv[3];
#pragma unroll
    for (int i = 0; i < 4; ++i) af[i] = *(const half8*)(smA[cur] + offA[i]);
#pragma unroll
    for (int g = 0; g < 3; ++g) bfv[g] = *(const half8*)(smB[cur] + offB[g]);
    if (t < 16){
#pragma unroll
      for (int g = 0; g < 3; ++g)
#pragma unroll
        for (int i = 0; i < 4; ++i)
          acc[g][i] = __builtin_amdgcn_mfma_f32_16x16x32_f16(af[i], bfv[g], acc[g][i], 0, 0, 0);
    } else {
#pragma unroll
      for (int i = 0; i < 4; ++i){
        acc[0][i] = __builtin_amdgcn_mfma_f32_16x16x32_f16(af[i], bfv[0], acc[0][i], 0, 0, 0);
        acc[1][i] = __builtin_amdgcn_mfma_f32_16x16x32_f16(af[i], bfv[1], acc[1][i], 0, 0, 0);
        accNI[i]  = __builtin_amdgcn_mfma_f32_16x16x32_f16(af[i], bfv[2], accNI[i], 0, 0, 0);
      }
    }
    asm volatile("s_waitcnt vmcnt(0)");
    __builtin_amdgcn_s_barrier();
  }
  int d = n0 + wn*16 + l15;
  float br  = bih[d] + bhh[d];
  float bz  = bih[512+d] + bhh[512+d];
  float bnh = bhh[1024+d];
  float bni = bih[1024+d];
#pragma unroll
  for (int i = 0; i < 4; ++i){
#pragma unroll
    for (int r = 0; r < 4; ++r){
      int m = m0 + wm*64 + i*16 + q*4 + r;
      float gr  = acc[0][i][r] + br;
      float gz  = acc[1][i][r] + bz;
      float hn  = acc[2][i][r] + bnh;
      float in_ = accNI[i][r] + bni;
      float rrv = sigmoidf_(gr);
      float zz  = sigmoidf_(gz);
      float nn  = tanhf_(in_ + rrv*hn);
      float hp  = (float)Abuf[(size_t)m*KC_ + d];
      H[(size_t)m*G_ + d] = (_Float16)((1.f-zz)*nn + zz*hp);
    }
  }
}

// ======================= 8-phase 256x256 FF GEMM ============================
// (R5-proven) BM=BN=256, BK=64, 8 waves (2M x 4N), per-wave 128x64 out.
#define STG_A8(T) do{ \
    __builtin_amdgcn_global_load_lds((gas_t)(pA0 + (T)*64),           (las_t)(&smA8[(T)&1][0] + wvid*1024),        16, 0, 0); \
    __builtin_amdgcn_global_load_lds((gas_t)(pA1 + (T)*64),           (las_t)(&smA8[(T)&1][0] + wvid*1024 + 512),  16, 0, 0); \
    __builtin_amdgcn_global_load_lds((gas_t)(pA0 + 128*G_ + (T)*64),  (las_t)(&smA8[(T)&1][0] + 8192 + wvid*1024), 16, 0, 0); \
    __builtin_amdgcn_global_load_lds((gas_t)(pA1 + 128*G_ + (T)*64),  (las_t)(&smA8[(T)&1][0] + 8192 + wvid*1024 + 512), 16, 0, 0); \
  }while(0)
#define STG_B8(T,H) do{ \
    __builtin_amdgcn_global_load_lds((gas_t)(pB0 + (H)*128*G_ + (T)*64), (las_t)(&smB8[(T)&1][0] + (H)*8192 + wvid*1024),       16, 0, 0); \
    __builtin_amdgcn_global_load_lds((gas_t)(pB1 + (H)*128*G_ + (T)*64), (las_t)(&smB8[(T)&1][0] + (H)*8192 + wvid*1024 + 512), 16, 0, 0); \
  }while(0)
#define RD_A8(DST, T, MF0) do{ \
    const _Float16* ba_ = &smA8[(T)&1][0]; \
    DST[0][0] = *(const half8*)(ba_ + aoff0 + (MF0)*1024); \
    DST[0][1] = *(const half8*)(ba_ + aoff1 + (MF0)*1024); \
    DST[1][0] = *(const half8*)(ba_ + aoff0 + ((MF0)+1)*1024); \
    DST[1][1] = *(const half8*)(ba_ + aoff1 + ((MF0)+1)*1024); \
  }while(0)
#define RD_B8(DST, T) do{ \
    const _Float16* bb_ = &smB8[(T)&1][0]; \
    _Pragma("unroll") \
    for (int nf_ = 0; nf_ < 4; ++nf_){ \
      DST[nf_][0] = *(const half8*)(bb_ + boff0 + nf_*1024); \
      DST[nf_][1] = *(const half8*)(bb_ + boff1 + nf_*1024); \
    } \
  }while(0)
#define MMQ8(AV, BV, MF0) do{ \
    _Pragma("unroll") \
    for (int u_ = 0; u_ < 2; ++u_) \
    _Pragma("unroll") \
    for (int nf_ = 0; nf_ < 4; ++nf_){ \
      acc[(MF0)+u_][nf_] = __builtin_amdgcn_mfma_f32_16x16x32_f16(AV[u_][0], BV[nf_][0], acc[(MF0)+u_][nf_], 0, 0, 0); \
      acc[(MF0)+u_][nf_] = __builtin_amdgcn_mfma_f32_16x16x32_f16(AV[u_][1], BV[nf_][1], acc[(MF0)+u_][nf_], 0, 0, 0); \
    } \
  }while(0)
#define PH_Q0(T, BC) do{ if ((T)+1 <= 7) STG_A8((T)+1); RD_A8(a_o, T, 2); \
    __builtin_amdgcn_s_barrier(); __builtin_amdgcn_s_setprio(1); MMQ8(a_e, BC, 0); \
    __builtin_amdgcn_s_setprio(0); __builtin_amdgcn_s_barrier(); }while(0)
#define PH_Q1(T, BC) do{ if ((T)+2 <= 7) STG_B8((T)+2, 0); RD_A8(a_e, T, 4); \
    __builtin_amdgcn_s_barrier(); __builtin_amdgcn_s_setprio(1); MMQ8(a_o, BC, 2); \
    __builtin_amdgcn_s_setprio(0); __builtin_amdgcn_s_barrier(); }while(0)
#define PH_Q2(T, BC) do{ if ((T)+2 <= 7) STG_B8((T)+2, 1); RD_A8(a_o, T, 6); \
    __builtin_amdgcn_s_barrier(); __builtin_amdgcn_s_setprio(1); MMQ8(a_e, BC, 4); \
    __builtin_amdgcn_s_setprio(0); __builtin_amdgcn_s_barrier(); }while(0)
#define PH_Q3(T, BC, BN) do{ \
    if ((T) < 7){ \
      if ((T) < 6) asm volatile("s_waitcnt vmcnt(4)" ::: "memory"); \
      else         asm volatile("s_waitcnt vmcnt(0)" ::: "memory"); \
      RD_B8(BN, (T)+1); RD_A8(a_e, (T)+1, 0); \
    } \
    __builtin_amdgcn_s_barrier(); __builtin_amdgcn_s_setprio(1); MMQ8(a_o, BC, 6); \
    __builtin_amdgcn_s_setprio(0); __builtin_amdgcn_s_barrier(); }while(0)
#define TILE8(T, BC, BN) do{ PH_Q0(T, BC); PH_Q1(T, BC); PH_Q2(T, BC); PH_Q3(T, BC, BN); }while(0)

#define K8_SETUP(Amat, Wmat) \
  int tid = threadIdx.x; \
  int lane = tid & 63, wvid = tid >> 6; \
  int wm = wvid & 1, wn = wvid >> 1; \
  int q = lane >> 4, l15 = lane & 15; \
  int x_ = l15 & 7; \
  int bid = blockIdx.x; \
  int wg = (bid & 7)*64 + (bid >> 3); \
  int mt = wg >> 1, nt = wg & 1; \
  int m0 = mt*256, n0 = nt*256; \
  int swzlo = (q ^ (x_ & 3))*8; \
  int aoff0 = (wm*128 + l15)*64 + ((0 ^ (x_>>2))*4)*8 + swzlo; \
  int aoff1 = (wm*128 + l15)*64 + ((1 ^ (x_>>2))*4)*8 + swzlo; \
  int boff0 = (wn*64 + l15)*64 + ((0 ^ (x_>>2))*4)*8 + swzlo; \
  int boff1 = (wn*64 + l15)*64 + ((1 ^ (x_>>2))*4)*8 + swzlo; \
  int srow = wvid*16 + (lane >> 3); \
  int sc = ((lane & 7) ^ ((lane >> 3) & 7))*8; \
  const _Float16* pA0 = Amat + (size_t)(m0 + srow)*G_ + sc; \
  const _Float16* pA1 = Amat + (size_t)(m0 + srow + 8)*G_ + sc; \
  const _Float16* pB0 = Wmat + (size_t)(n0 + srow)*G_ + sc; \
  const _Float16* pB1 = Wmat + (size_t)(n0 + srow + 8)*G_ + sc; \
  floatx4 acc[8][4] = {}; \
  half8 a_e[2][2], a_o[2][2], bA[4][2], bB[4][2]; \
  STG_A8(0); STG_B8(0,0); STG_B8(0,1); STG_B8(1,0); STG_B8(1,1); \
  asm volatile("s_waitcnt vmcnt(4)" ::: "memory"); \
  __builtin_amdgcn_s_barrier(); \
  RD_B8(bA, 0); RD_A8(a_e, 0, 0); \
  TILE8(0, bA, bB); TILE8(1, bB, bA); \
  TILE8(2, bA, bB); TILE8(3, bB, bA); \
  TILE8(4, bA, bB); TILE8(5, bB, bA); \
  TILE8(6, bA, bB); TILE8(7, bB, bA);

// ---------------- K3: FF GEMM 8-phase  Out = relu(A@W^T+b) ------------------
__global__ __launch_bounds__(512, 2) void k_gemm8(
    const _Float16* __restrict__ A, const _Float16* __restrict__ W,
    const float* __restrict__ bias, _Float16* __restrict__ Out){
  __shared__ _Float16 smA8[2][SMH];   // 64 KB
  __shared__ _Float16 smB8[2][SMH];   // 64 KB
  K8_SETUP(A, W)
  float bv[4];
#pragma unroll
  for (int nf = 0; nf < 4; ++nf) bv[nf] = bias[n0 + wn*64 + nf*16 + l15];
#pragma unroll
  for (int mf = 0; mf < 8; ++mf){
    int m = m0 + wm*128 + mf*16 + q*4;
#pragma unroll
    for (int nf = 0; nf < 4; ++nf){
      int n = n0 + wn*64 + nf*16 + l15;
#pragma unroll
      for (int r = 0; r < 4; ++r)
        Out[(size_t)(m+r)*G_ + n] = (_Float16)fmaxf(acc[mf][nf][r] + bv[nf], 0.f);
    }
  }
}

// ---------------- K3b: FF3 8-phase GEMM + LN/score partials -----------------
__global__ __launch_bounds__(512, 2) void k_ff38(
    const _Float16* __restrict__ A, const _Float16* __restrict__ W,
    const float* __restrict__ bias, const float* __restrict__ ln_pre_g,
    const float* __restrict__ Ws, float* __restrict__ Pbuf){
  __shared__ _Float16 smA8[2][SMH];
  __shared__ _Float16 smB8[2][SMH];
  K8_SETUP(A, W)
  float gws[4], bv[4];
#pragma unroll
  for (int nf = 0; nf < 4; ++nf){
    int n = n0 + wn*64 + nf*16 + l15;
    gws[nf] = ln_pre_g[n]*Ws[n];
    bv[nf] = bias[n];
  }
  float* sP = (float*)&smB8[0][0];   // reuse: [256 rows][4 wn][3], 12 KB
#pragma unroll
  for (int mf = 0; mf < 8; ++mf){
#pragma unroll
    for (int r = 0; r < 4; ++r){
      float p1 = 0.f, p2 = 0.f, p3 = 0.f;
#pragma unroll
      for (int nf = 0; nf < 4; ++nf){
        float xv = fmaxf(acc[mf][nf][r] + bv[nf], 0.f);
        p1 += xv; p2 += xv*xv; p3 += gws[nf]*xv;
      }
#pragma unroll
      for (int off = 1; off < 16; off <<= 1){
        p1 += __shfl_xor(p1, off);
        p2 += __shfl_xor(p2, off);
        p3 += __shfl_xor(p3, off);
      }
      if (l15 == 0){
        int rl = wm*128 + mf*16 + q*4 + r;
        sP[(rl*4 + wn)*3 + 0] = p1;
        sP[(rl*4 + wn)*3 + 1] = p2;
        sP[(rl*4 + wn)*3 + 2] = p3;
      }
    }
  }
  __syncthreads();
  if (tid < 256){
    int m = m0 + tid;
    float* dst = Pbuf + ((size_t)m*2 + nt)*3;
#pragma unroll
    for (int c = 0; c < 3; ++c)
      dst[c] = sP[(tid*4+0)*3+c] + sP[(tid*4+1)*3+c] +
               sP[(tid*4+2)*3+c] + sP[(tid*4+3)*3+c];
  }
}

// ---------------- K4: finish scores from partials + zero spect --------------
__global__ __launch_bounds__(256) void k_score_fin(
    const float* __restrict__ Pbuf, const float* __restrict__ g,
    const float* __restrict__ bta, const float* __restrict__ Ws,
    const float* __restrict__ bs, float* __restrict__ scores,
    float* __restrict__ spect){
  __shared__ float red[8];
  int tid = threadIdx.x, lane = tid & 63, wv = tid >> 6;
  if (blockIdx.x < 32) spect[(size_t)blockIdx.x*256 + tid] = 0.f;
  int i0 = tid*2;
  float c1p = g[i0]*Ws[i0] + g[i0+1]*Ws[i0+1];
  float c2p = bta[i0]*Ws[i0] + bta[i0+1]*Ws[i0+1];
  c1p = wave_sum_f(c1p); c2p = wave_sum_f(c2p);
  if (lane == 0){ red[wv] = c1p; red[4+wv] = c2p; }
  __syncthreads();
  float c1 = red[0]+red[1]+red[2]+red[3];
  float c2 = red[4]+red[5]+red[6]+red[7] + bs[0];
  size_t row = (size_t)blockIdx.x*256 + tid;
  const float* p = Pbuf + row*6;
  float2 u0 = *(const float2*)p;
  float2 u1 = *(const float2*)(p+2);
  float2 u2 = *(const float2*)(p+4);
  float P1 = u0.x + u1.y;
  float P2 = u0.y + u2.x;
  float P3 = u1.x + u2.y;
  float mu = P1*(1.f/512.f);
  float var = P2*(1.f/512.f) - mu*mu;
  float rs = rsqrtf(var + 1e-5f);
  scores[row] = rs*(P3 - mu*c1) + c2;
}

// ---------------- K5: softmax over S per batch (1024 threads) ---------------
__global__ __launch_bounds__(1024) void k_softmax(
    const float* __restrict__ scores, float* __restrict__ probs){
  __shared__ float red[16];
  int b = blockIdx.x, tid = threadIdx.x, lane = tid & 63, wv = tid >> 6;
  const float* sp = scores + (size_t)b*S_;
  float* pp = probs + (size_t)b*S_;
  float mx = -1e30f;
  for (int i = tid; i < S_; i += 1024) mx = fmaxf(mx, sp[i]);
  mx = wave_max_f(mx);
  if (lane == 0) red[wv] = mx;
  __syncthreads();
  float m2 = red[0];
#pragma unroll
  for (int k = 1; k < 16; ++k) m2 = fmaxf(m2, red[k]);
  __syncthreads();
  float sum = 0.f;
  for (int i = tid; i < S_; i += 1024){
    float e = __expf(sp[i]-m2);
    pp[i] = e;
    sum += e;
  }
  sum = wave_sum_f(sum);
  if (lane == 0) red[wv] = sum;
  __syncthreads();
  float s2 = 0.f;
#pragma unroll
  for (int k = 0; k < 16; ++k) s2 += red[k];
  float inv = 1.f/s2;
  for (int i = tid; i < S_; i += 1024)
    pp[i] *= inv;
}

// ---------------- K6: spectrum scatter (parallelized 8x) --------------------
__global__ __launch_bounds__(256) void k_spect_p(
    const float* __restrict__ peaks, const float* __restrict__ probs,
    float* __restrict__ spect){
  __shared__ float bins[512];
  int b = blockIdx.x, chunk = blockIdx.y, tid = threadIdx.x;
  bins[tid] = 0.f; bins[tid+256] = 0.f;
  __syncthreads();
  int s0 = chunk*(S_/8);
  for (int i = tid; i < (S_/8)*M_; i += 256){
    int s = s0 + (i >> 3), m = i & 7;
    const float* pk = peaks + (((size_t)b*S_ + s)*M_ + m)*2;
    float mass = pk[0], inten = pk[1];
    float p = probs[(size_t)b*S_ + s];
    int bin = (int)rintf(mass);
    bin = min(max(bin, 0), 511);
    atomicAdd(&bins[bin], inten*p);
  }
  __syncthreads();
  atomicAdd(&spect[(size_t)b*512 + tid],       bins[tid]);
  atomicAdd(&spect[(size_t)b*512 + tid + 256], bins[tid+256]);
}

// ---------------- launcher --------------------------------------------------
extern "C" void kernel_launch(void* const* d_in, const int* in_sizes, int n_in,
                              void* d_out, int out_size, void* d_ws, size_t ws_size,
                              hipStream_t stream) {
  const float* vf       = (const float*)d_in[0];
  const float* mask     = (const float*)d_in[1];
  const float* eoh      = (const float*)d_in[2];
  const float* subs     = (const float*)d_in[4];
  const float* peaks    = (const float*)d_in[5];
  const float* ln_sub_g = (const float*)d_in[6];
  const float* ln_sub_b = (const float*)d_in[7];
  const float* W_ih     = (const float*)d_in[8];
  const float* W_hh     = (const float*)d_in[9];
  const float* b_ih     = (const float*)d_in[10];
  const float* b_hh     = (const float*)d_in[11];
  const float* W1       = (const float*)d_in[12];
  const float* b1       = (const float*)d_in[13];
  const float* W2a      = (const float*)d_in[14];
  const float* b2a      = (const float*)d_in[15];
  const float* W2b      = (const float*)d_in[16];
  const float* b2b      = (const float*)d_in[17];
  const float* ln_pre_g = (const float*)d_in[18];
  const float* ln_pre_b = (const float*)d_in[19];
  const float* Ws       = (const float*)d_in[20];
  const float* bs       = (const float*)d_in[21];
  float* out = (float*)d_out;            // [0,8192) spect, [8192,73728) probs
  float* probs_out = out + (size_t)B_*512;

  // workspace carve — ~158 MB (ws >= ~206 MB proven)
  char* w = (char*)d_ws;
  float* scores = (float*)w;     w += (size_t)BS_*4;
  float* Pbuf   = (float*)w;     w += (size_t)BS_*12*4;        // 3 MB (uses 6/row)
  _Float16* Wcat = (_Float16*)w; w += (size_t)NG_*KC_*2;       // ~2 MB
  _Float16* W1h  = (_Float16*)w; w += (size_t)G_*G_*2;
  _Float16* W2ah = (_Float16*)w; w += (size_t)G_*G_*2;
  _Float16* W2bh = (_Float16*)w; w += (size_t)G_*G_*2;
  _Float16* Abuf = (_Float16*)w; w += (size_t)BS_*KC_*2;       // 84 MB
  _Float16* bufh0 = (_Float16*)w;                              // 67 MB (H)
  _Float16* bufh1 = Abuf;        // x1 reuses A region (84 >= 67 MB)

  k_cvtw<<<dim3(256, 4), 256, 0, stream>>>(W1, W2a, W2b, W1h, W_hh, W_ih, Wcat);
  k_prep_mfma<<<dim3(S_/128, B_), 256, 0, stream>>>(vf, mask, eoh, subs,
                                                    ln_sub_g, ln_sub_b, Abuf);
  k_gru_fused<<<dim3(8, 512), 512, 0, stream>>>(Abuf, Wcat, b_ih, b_hh, bufh0);
  k_gemm8<<<512, 512, 0, stream>>>(bufh0, W1h,  b1,  bufh1);   // x1
  k_gemm8<<<512, 512, 0, stream>>>(bufh1, W2ah, b2a, bufh0);   // x2
  k_ff38<<<512, 512, 0, stream>>>(bufh0, W2bh, b2b, ln_pre_g, Ws, Pbuf);
  k_score_fin<<<BS_/256, 256, 0, stream>>>(Pbuf, ln_pre_g, ln_pre_b, Ws, bs,
                                           scores, out);
  k_softmax<<<B_, 1024, 0, stream>>>(scores, probs_out);
  k_spect_p<<<dim3(B_, 8), 256, 0, stream>>>(peaks, probs_out, out);
}

// Round 9
// 464.943 us; speedup vs baseline: 1.0413x; 1.0028x over previous
//
#include <hip/hip_runtime.h>
#include <math.h>

#define B_ 16
#define A_ 32
#define G_ 512
#define S_ 4096
#define M_ 8
#define BS_ 65536
#define KC_ 640      // concat K: 512 normed + 100 OH + 28 pad
#define NG_ 1536
#define SMH 16384    // halfs per LDS buffer per matrix (256 rows x 64 halfs)

typedef _Float16 half8 __attribute__((ext_vector_type(8)));
typedef _Float16 half4v __attribute__((ext_vector_type(4)));
typedef _Float16 half2v __attribute__((ext_vector_type(2)));
typedef float floatx4 __attribute__((ext_vector_type(4)));

typedef const __attribute__((address_space(1))) void* gas_t;
typedef __attribute__((address_space(3))) void* las_t;

// ---------------- helpers ----------------
__device__ __forceinline__ float wave_sum_f(float v){
#pragma unroll
  for (int o = 32; o > 0; o >>= 1) v += __shfl_xor(v, o);
  return v;
}
__device__ __forceinline__ float wave_max_f(float v){
#pragma unroll
  for (int o = 32; o > 0; o >>= 1) v = fmaxf(v, __shfl_xor(v, o));
  return v;
}
__device__ __forceinline__ float sigmoidf_(float x){ return 1.f/(1.f+__expf(-x)); }
__device__ __forceinline__ float tanhf_(float x){ return 1.f - 2.f/(__expf(2.f*x)+1.f); }

// ---------------- K0: fp32 -> fp16 convert (3 G*G) + Wcat build -------------
// grid (256, 4): y in {0,1,2} converts matrix y into d; y==3 builds
// Wcat[1536][640] = [W_hh | W_ih | 0] (6 rows per block).
__global__ __launch_bounds__(256) void k_cvtw(const float* __restrict__ s0,
                                              const float* __restrict__ s1,
                                              const float* __restrict__ s2,
                                              _Float16* __restrict__ d,
                                              const float* __restrict__ Whh,
                                              const float* __restrict__ Wih,
                                              _Float16* __restrict__ Wcat){
  if (blockIdx.y == 3){
    int j0 = blockIdx.x*6;
    for (int j = j0; j < j0+6; ++j)
      for (int p = threadIdx.x; p < KC_; p += 256){
        float v = 0.f;
        if (p < 512) v = Whh[(size_t)j*512 + p];
        else if (p < 612) v = Wih[(size_t)j*100 + (p - 512)];
        Wcat[(size_t)j*KC_ + p] = (_Float16)v;
      }
    return;
  }
  const float* s = (blockIdx.y == 0) ? s0 : (blockIdx.y == 1) ? s1 : s2;
  int i = (blockIdx.x*256 + threadIdx.x)*4;
  if (i >= G_*G_) return;
  float4 v = *(const float4*)(s+i);
  half4v o; o[0]=(_Float16)v.x; o[1]=(_Float16)v.y; o[2]=(_Float16)v.z; o[3]=(_Float16)v.w;
  *(half4v*)(d + (size_t)blockIdx.y*G_*G_ + i) = o;
}

// ---------------- K1: MFMA prep — swvs GEMM + LN + counts + OH --------------
// Epilogue (R9): LN output staged per-gi in LDS (aliasing dead s_mvfT,
// stride 528 halfs = conflict-free across q-rows), then cooperatively
// stored as half8 full-row-coalesced writes. Values bit-identical to the
// old per-element store path (same arithmetic, same cvt).
__global__ __launch_bounds__(256) void k_prep_mfma(
    const float* __restrict__ vf, const float* __restrict__ mask,
    const float* __restrict__ eoh, const float* __restrict__ subs,
    const float* __restrict__ ln_g, const float* __restrict__ ln_b,
    _Float16* __restrict__ Abuf){
  __shared__ _Float16 s_mvfT[G_*A_];   // [g][a], masked vf, 32 KB (dead after bf load -> reused as stage)
  __shared__ _Float16 s_sm[128*A_];    // [s][a], raw subs, 8 KB
  __shared__ float s_m[A_];
  __shared__ float s_e[A_*5];
  __shared__ float s_ssum[128];
  __shared__ float s_red1[2][4][16];
  __shared__ float s_red2[2][4][16];
  int tid = threadIdx.x;
  int bx = blockIdx.x, b = blockIdx.y;
  int lane = tid & 63, w = tid >> 6;
  int q = lane >> 4, l15 = lane & 15;
  size_t row0 = (size_t)b*S_ + (size_t)bx*128;
  if (tid < A_)   s_m[tid] = mask[b*A_ + tid];
  if (tid < A_*5) s_e[tid] = eoh[b*A_*5 + tid];
  __syncthreads();
  {
    int p = tid & 15, gseg = tid >> 4;
    float mk0 = s_m[2*p], mk1 = s_m[2*p+1];
    const float* v0 = vf + ((size_t)b*A_ + 2*p)*G_ + gseg*32;
    const float* v1 = v0 + G_;
#pragma unroll
    for (int i = 0; i < 32; i += 4){
      float4 a = *(const float4*)(v0 + i);
      float4 c = *(const float4*)(v1 + i);
      float av[4] = {a.x, a.y, a.z, a.w};
      float cv[4] = {c.x, c.y, c.z, c.w};
#pragma unroll
      for (int j = 0; j < 4; ++j){
        half2v h; h[0] = (_Float16)(av[j]*mk0); h[1] = (_Float16)(cv[j]*mk1);
        *(half2v*)(s_mvfT + (gseg*32 + i + j)*A_ + 2*p) = h;
      }
    }
  }
  {
    int s = tid >> 1, hh = tid & 1;
    const float* sp = subs + (row0 + s)*A_ + hh*16;
    _Float16* dst = s_sm + s*A_ + hh*16;
#pragma unroll
    for (int i = 0; i < 16; i += 4){
      float4 v = *(const float4*)(sp + i);
      half4v h; h[0]=(_Float16)v.x; h[1]=(_Float16)v.y; h[2]=(_Float16)v.z; h[3]=(_Float16)v.w;
      *(half4v*)(dst + i) = h;
    }
  }
  __syncthreads();
  if (tid < 128){
    int s = tid;
    float ssum = 0.f, c0=0.f, c1=0.f, c2=0.f, c3=0.f, c4=0.f;
#pragma unroll
    for (int a = 0; a < A_; ++a){
      float v = (float)s_sm[s*A_ + a];
      ssum += v * s_m[a];
      c0 += v * s_e[a*5+0]; c1 += v * s_e[a*5+1]; c2 += v * s_e[a*5+2];
      c3 += v * s_e[a*5+3]; c4 += v * s_e[a*5+4];
    }
    int cc[5];
    cc[0] = min(max((int)(c0+0.5f),0),19); cc[1] = min(max((int)(c1+0.5f),0),19);
    cc[2] = min(max((int)(c2+0.5f),0),19); cc[3] = min(max((int)(c3+0.5f),0),19);
    cc[4] = min(max((int)(c4+0.5f),0),19);
    s_ssum[s] = ssum;
    _Float16* dst = Abuf + (row0 + s)*KC_ + 512;
#pragma unroll
    for (int t = 0; t < 16; ++t){
      half8 hv;
#pragma unroll
      for (int u = 0; u < 8; ++u){
        int k = t*8 + u;
        float v = 0.f;
        if (k < 100){ int f = k/20, l = k - f*20; v = (l <= cc[f]) ? 1.f : 0.f; }
        hv[u] = (_Float16)v;
      }
      *(half8*)(dst + t*8) = hv;
    }
  }
  half8 bf[8]; float lng[8], lnb[8];
#pragma unroll
  for (int t = 0; t < 8; ++t){
    int g = w*128 + t*16 + l15;
    bf[t] = *(const half8*)(s_mvfT + g*A_ + q*8);
    lng[t] = ln_g[g]; lnb[t] = ln_b[g];
  }
  __syncthreads();
  // s_mvfT dead from here: alias as the per-gi LN-output staging tile.
  _Float16* s_stage = s_mvfT;   // [16 rows][528 stride] = 16.5 KB < 32 KB
  for (int gi = 0; gi < 8; ++gi){
    half8 af = *(const half8*)(s_sm + (gi*16 + l15)*A_ + q*8);
    floatx4 c[8];
#pragma unroll
    for (int t = 0; t < 8; ++t){
      floatx4 z = {0.f, 0.f, 0.f, 0.f};
      c[t] = __builtin_amdgcn_mfma_f32_16x16x32_f16(af, bf[t], z, 0, 0, 0);
    }
    float p1[4] = {0.f,0.f,0.f,0.f}, p2[4] = {0.f,0.f,0.f,0.f};
#pragma unroll
    for (int t = 0; t < 8; ++t)
#pragma unroll
      for (int r = 0; r < 4; ++r){ float v = c[t][r]; p1[r] += v; p2[r] += v*v; }
#pragma unroll
    for (int off = 1; off < 16; off <<= 1)
#pragma unroll
      for (int r = 0; r < 4; ++r){
        p1[r] += __shfl_xor(p1[r], off);
        p2[r] += __shfl_xor(p2[r], off);
      }
    int gb = gi & 1;
    if (l15 == 0){
#pragma unroll
      for (int r = 0; r < 4; ++r){ s_red1[gb][w][q*4+r] = p1[r]; s_red2[gb][w][q*4+r] = p2[r]; }
    }
    __syncthreads();
#pragma unroll
    for (int r = 0; r < 4; ++r){
      int sl = gi*16 + q*4 + r;
      int rr = q*4 + r;
      float t1 = s_red1[gb][0][rr] + s_red1[gb][1][rr] + s_red1[gb][2][rr] + s_red1[gb][3][rr];
      float t2 = s_red2[gb][0][rr] + s_red2[gb][1][rr] + s_red2[gb][2][rr] + s_red2[gb][3][rr];
      float inv = 1.f/(s_ssum[sl] + 1e-4f);
      float mu = t1*inv*(1.f/512.f);
      float var = t2*inv*inv*(1.f/512.f) - mu*mu;
      float rs = rsqrtf(var + 1e-5f);
      _Float16* srow = s_stage + (q*4 + r)*528;
#pragma unroll
      for (int t = 0; t < 8; ++t){
        float o = (c[t][r]*inv - mu)*rs*lng[t] + lnb[t];
        srow[w*128 + t*16 + l15] = (_Float16)o;
      }
    }
    __syncthreads();
    // cooperative coalesced store: 16 rows x 512 halfs, half8 per thread x4
#pragma unroll
    for (int k = 0; k < 4; ++k){
      int v = tid + k*256;                  // 0..1023
      int row = v >> 6, c8 = (v & 63)*8;
      *(half8*)(Abuf + (row0 + gi*16 + row)*KC_ + c8) =
          *(const half8*)(s_stage + row*528 + c8);
    }
  }
}

// ---------------- K2: fused (gh+gi) GEMM (3 gates) + GRU elementwise --------
// 2-phase double-buffered pipeline (R1-proven, best of 3 measured schedules:
// 197.5 vs 203.3 (8-phase) vs 209.7 (1-barrier/tile)): stage tile t+1 while
// computing tile t; one vmcnt(0)+s_barrier per K-step. 40 KB LDS -> 4 blk/CU.
__global__ __launch_bounds__(512) void k_gru_fused(
    const _Float16* __restrict__ Abuf, const _Float16* __restrict__ Wcat,
    const float* __restrict__ bih, const float* __restrict__ bhh,
    _Float16* __restrict__ H){
  __shared__ _Float16 smA[2][128*32];   // 16 KB
  __shared__ _Float16 smB[2][192*32];   // 24 KB
  int tid = threadIdx.x;
  int lane = tid & 63, wvid = tid >> 6;      // 8 waves
  int wm = wvid & 1, wn = wvid >> 1;
  int q = lane >> 4, l15 = lane & 15;
  int mt = blockIdx.x*64 + (blockIdx.y >> 3);
  int dt = blockIdx.y & 7;
  int m0 = mt*128, n0 = dt*64;
  floatx4 acc[3][4] = {};
  floatx4 accNI[4] = {};
  int offA[4], offB[3];
#pragma unroll
  for (int i = 0; i < 4; ++i){
    int r = wm*64 + i*16 + l15;
    offA[i] = (r*4 + (q ^ ((r>>2)&3)))*8;
  }
#pragma unroll
  for (int g = 0; g < 3; ++g){
    int rb = g*64 + wn*16 + l15;
    offB[g] = (rb*4 + (q ^ ((rb>>2)&3)))*8;
  }
  const _Float16* gA;
  {
    int u = wvid*64 + lane;
    int r = u >> 2, c = (u & 3) ^ ((r >> 2) & 3);
    gA = Abuf + (size_t)(m0 + r)*KC_ + c*8;
  }
  const _Float16* gB0;
  {
    int u = wvid*64 + lane;
    int rb = u >> 2, c = (u & 3) ^ ((rb >> 2) & 3);
    int grow = (rb >> 6)*512 + n0 + (rb & 63);
    gB0 = Wcat + (size_t)grow*KC_ + c*8;
  }
  const _Float16* gB1 = nullptr;
  if (wvid < 4){
    int u = (8 + wvid)*64 + lane;
    int rb = u >> 2, c = (u & 3) ^ ((rb >> 2) & 3);
    int grow = (rb >> 6)*512 + n0 + (rb & 63);
    gB1 = Wcat + (size_t)grow*KC_ + c*8;
  }
  // prologue: stage tile 0 into buf 0
  __builtin_amdgcn_global_load_lds((gas_t)gA,  (las_t)(smA[0] + wvid*512), 16, 0, 0);
  __builtin_amdgcn_global_load_lds((gas_t)gB0, (las_t)(smB[0] + wvid*512), 16, 0, 0);
  if (wvid < 4)
    __builtin_amdgcn_global_load_lds((gas_t)gB1, (las_t)(smB[0] + (8+wvid)*512), 16, 0, 0);
  asm volatile("s_waitcnt vmcnt(0)");
  __builtin_amdgcn_s_barrier();
  const int NT = KC_/32;   // 20 (tail phase from t=16)
  for (int t = 0; t < NT; ++t){
    int cur = t & 1;
    if (t + 1 < NT){
      int kc = (t+1)*32;
      __builtin_amdgcn_global_load_lds((gas_t)(gA + kc),  (las_t)(smA[cur^1] + wvid*512), 16, 0, 0);
      __builtin_amdgcn_global_load_lds((gas_t)(gB0 + kc), (las_t)(smB[cur^1] + wvid*512), 16, 0, 0);
      if (wvid < 4)
        __builtin_amdgcn_global_load_lds((gas_t)(gB1 + kc), (las_t)(smB[cur^1] + (8+wvid)*512), 16, 0, 0);
    }
    half8 af[4], bfv[3];
#pragma unroll
    for (int i = 0; i < 4; ++i) af[i] = *(const half8*)(smA[cur] + offA[i]);
#pragma unroll
    for (int g = 0; g < 3; ++g) bfv[g] = *(const half8*)(smB[cur] + offB[g]);
    if (t < 16){
#pragma unroll
      for (int g = 0; g < 3; ++g)
#pragma unroll
        for (int i = 0; i < 4; ++i)
          acc[g][i] = __builtin_amdgcn_mfma_f32_16x16x32_f16(af[i], bfv[g], acc[g][i], 0, 0, 0);
    } else {
#pragma unroll
      for (int i = 0; i < 4; ++i){
        acc[0][i] = __builtin_amdgcn_mfma_f32_16x16x32_f16(af[i], bfv[0], acc[0][i], 0, 0, 0);
        acc[1][i] = __builtin_amdgcn_mfma_f32_16x16x32_f16(af[i], bfv[1], acc[1][i], 0, 0, 0);
        accNI[i]  = __builtin_amdgcn_mfma_f32_16x16x32_f16(af[i], bfv[2], accNI[i], 0, 0, 0);
      }
    }
    asm volatile("s_waitcnt vmcnt(0)");
    __builtin_amdgcn_s_barrier();
  }
  int d = n0 + wn*16 + l15;
  float br  = bih[d] + bhh[d];
  float bz  = bih[512+d] + bhh[512+d];
  float bnh = bhh[1024+d];
  float bni = bih[1024+d];
#pragma unroll
  for (int i = 0; i < 4; ++i){
#pragma unroll
    for (int r = 0; r < 4; ++r){
      int m = m0 + wm*64 + i*16 + q*4 + r;
      float gr  = acc[0][i][r] + br;
      float gz  = acc[1][i][r] + bz;
      float hn  = acc[2][i][r] + bnh;
      float in_ = accNI[i][r] + bni;
      float rrv = sigmoidf_(gr);
      float zz  = sigmoidf_(gz);
      float nn  = tanhf_(in_ + rrv*hn);
      float hp  = (float)Abuf[(size_t)m*KC_ + d];
      H[(size_t)m*G_ + d] = (_Float16)((1.f-zz)*nn + zz*hp);
    }
  }
}

// ======================= 8-phase 256x256 FF GEMM ============================
// (R5-proven) BM=BN=256, BK=64, 8 waves (2M x 4N), per-wave 128x64 out.
#define STG_A8(T) do{ \
    __builtin_amdgcn_global_load_lds((gas_t)(pA0 + (T)*64),           (las_t)(&smA8[(T)&1][0] + wvid*1024),        16, 0, 0); \
    __builtin_amdgcn_global_load_lds((gas_t)(pA1 + (T)*64),           (las_t)(&smA8[(T)&1][0] + wvid*1024 + 512),  16, 0, 0); \
    __builtin_amdgcn_global_load_lds((gas_t)(pA0 + 128*G_ + (T)*64),  (las_t)(&smA8[(T)&1][0] + 8192 + wvid*1024), 16, 0, 0); \
    __builtin_amdgcn_global_load_lds((gas_t)(pA1 + 128*G_ + (T)*64),  (las_t)(&smA8[(T)&1][0] + 8192 + wvid*1024 + 512), 16, 0, 0); \
  }while(0)
#define STG_B8(T,H) do{ \
    __builtin_amdgcn_global_load_lds((gas_t)(pB0 + (H)*128*G_ + (T)*64), (las_t)(&smB8[(T)&1][0] + (H)*8192 + wvid*1024),       16, 0, 0); \
    __builtin_amdgcn_global_load_lds((gas_t)(pB1 + (H)*128*G_ + (T)*64), (las_t)(&smB8[(T)&1][0] + (H)*8192 + wvid*1024 + 512), 16, 0, 0); \
  }while(0)
#define RD_A8(DST, T, MF0) do{ \
    const _Float16* ba_ = &smA8[(T)&1][0]; \
    DST[0][0] = *(const half8*)(ba_ + aoff0 + (MF0)*1024); \
    DST[0][1] = *(const half8*)(ba_ + aoff1 + (MF0)*1024); \
    DST[1][0] = *(const half8*)(ba_ + aoff0 + ((MF0)+1)*1024); \
    DST[1][1] = *(const half8*)(ba_ + aoff1 + ((MF0)+1)*1024); \
  }while(0)
#define RD_B8(DST, T) do{ \
    const _Float16* bb_ = &smB8[(T)&1][0]; \
    _Pragma("unroll") \
    for (int nf_ = 0; nf_ < 4; ++nf_){ \
      DST[nf_][0] = *(const half8*)(bb_ + boff0 + nf_*1024); \
      DST[nf_][1] = *(const half8*)(bb_ + boff1 + nf_*1024); \
    } \
  }while(0)
#define MMQ8(AV, BV, MF0) do{ \
    _Pragma("unroll") \
    for (int u_ = 0; u_ < 2; ++u_) \
    _Pragma("unroll") \
    for (int nf_ = 0; nf_ < 4; ++nf_){ \
      acc[(MF0)+u_][nf_] = __builtin_amdgcn_mfma_f32_16x16x32_f16(AV[u_][0], BV[nf_][0], acc[(MF0)+u_][nf_], 0, 0, 0); \
      acc[(MF0)+u_][nf_] = __builtin_amdgcn_mfma_f32_16x16x32_f16(AV[u_][1], BV[nf_][1], acc[(MF0)+u_][nf_], 0, 0, 0); \
    } \
  }while(0)
#define PH_Q0(T, BC) do{ if ((T)+1 <= 7) STG_A8((T)+1); RD_A8(a_o, T, 2); \
    __builtin_amdgcn_s_barrier(); __builtin_amdgcn_s_setprio(1); MMQ8(a_e, BC, 0); \
    __builtin_amdgcn_s_setprio(0); __builtin_amdgcn_s_barrier(); }while(0)
#define PH_Q1(T, BC) do{ if ((T)+2 <= 7) STG_B8((T)+2, 0); RD_A8(a_e, T, 4); \
    __builtin_amdgcn_s_barrier(); __builtin_amdgcn_s_setprio(1); MMQ8(a_o, BC, 2); \
    __builtin_amdgcn_s_setprio(0); __builtin_amdgcn_s_barrier(); }while(0)
#define PH_Q2(T, BC) do{ if ((T)+2 <= 7) STG_B8((T)+2, 1); RD_A8(a_o, T, 6); \
    __builtin_amdgcn_s_barrier(); __builtin_amdgcn_s_setprio(1); MMQ8(a_e, BC, 4); \
    __builtin_amdgcn_s_setprio(0); __builtin_amdgcn_s_barrier(); }while(0)
#define PH_Q3(T, BC, BN) do{ \
    if ((T) < 7){ \
      if ((T) < 6) asm volatile("s_waitcnt vmcnt(4)" ::: "memory"); \
      else         asm volatile("s_waitcnt vmcnt(0)" ::: "memory"); \
      RD_B8(BN, (T)+1); RD_A8(a_e, (T)+1, 0); \
    } \
    __builtin_amdgcn_s_barrier(); __builtin_amdgcn_s_setprio(1); MMQ8(a_o, BC, 6); \
    __builtin_amdgcn_s_setprio(0); __builtin_amdgcn_s_barrier(); }while(0)
#define TILE8(T, BC, BN) do{ PH_Q0(T, BC); PH_Q1(T, BC); PH_Q2(T, BC); PH_Q3(T, BC, BN); }while(0)

#define K8_SETUP(Amat, Wmat) \
  int tid = threadIdx.x; \
  int lane = tid & 63, wvid = tid >> 6; \
  int wm = wvid & 1, wn = wvid >> 1; \
  int q = lane >> 4, l15 = lane & 15; \
  int x_ = l15 & 7; \
  int bid = blockIdx.x; \
  int wg = (bid & 7)*64 + (bid >> 3); \
  int mt = wg >> 1, nt = wg & 1; \
  int m0 = mt*256, n0 = nt*256; \
  int swzlo = (q ^ (x_ & 3))*8; \
  int aoff0 = (wm*128 + l15)*64 + ((0 ^ (x_>>2))*4)*8 + swzlo; \
  int aoff1 = (wm*128 + l15)*64 + ((1 ^ (x_>>2))*4)*8 + swzlo; \
  int boff0 = (wn*64 + l15)*64 + ((0 ^ (x_>>2))*4)*8 + swzlo; \
  int boff1 = (wn*64 + l15)*64 + ((1 ^ (x_>>2))*4)*8 + swzlo; \
  int srow = wvid*16 + (lane >> 3); \
  int sc = ((lane & 7) ^ ((lane >> 3) & 7))*8; \
  const _Float16* pA0 = Amat + (size_t)(m0 + srow)*G_ + sc; \
  const _Float16* pA1 = Amat + (size_t)(m0 + srow + 8)*G_ + sc; \
  const _Float16* pB0 = Wmat + (size_t)(n0 + srow)*G_ + sc; \
  const _Float16* pB1 = Wmat + (size_t)(n0 + srow + 8)*G_ + sc; \
  floatx4 acc[8][4] = {}; \
  half8 a_e[2][2], a_o[2][2], bA[4][2], bB[4][2]; \
  STG_A8(0); STG_B8(0,0); STG_B8(0,1); STG_B8(1,0); STG_B8(1,1); \
  asm volatile("s_waitcnt vmcnt(4)" ::: "memory"); \
  __builtin_amdgcn_s_barrier(); \
  RD_B8(bA, 0); RD_A8(a_e, 0, 0); \
  TILE8(0, bA, bB); TILE8(1, bB, bA); \
  TILE8(2, bA, bB); TILE8(3, bB, bA); \
  TILE8(4, bA, bB); TILE8(5, bB, bA); \
  TILE8(6, bA, bB); TILE8(7, bB, bA);

// ---------------- K3: FF GEMM 8-phase  Out = relu(A@W^T+b) ------------------
__global__ __launch_bounds__(512, 2) void k_gemm8(
    const _Float16* __restrict__ A, const _Float16* __restrict__ W,
    const float* __restrict__ bias, _Float16* __restrict__ Out){
  __shared__ _Float16 smA8[2][SMH];   // 64 KB
  __shared__ _Float16 smB8[2][SMH];   // 64 KB
  K8_SETUP(A, W)
  float bv[4];
#pragma unroll
  for (int nf = 0; nf < 4; ++nf) bv[nf] = bias[n0 + wn*64 + nf*16 + l15];
#pragma unroll
  for (int mf = 0; mf < 8; ++mf){
    int m = m0 + wm*128 + mf*16 + q*4;
#pragma unroll
    for (int nf = 0; nf < 4; ++nf){
      int n = n0 + wn*64 + nf*16 + l15;
#pragma unroll
      for (int r = 0; r < 4; ++r)
        Out[(size_t)(m+r)*G_ + n] = (_Float16)fmaxf(acc[mf][nf][r] + bv[nf], 0.f);
    }
  }
}

// ---------------- K3b: FF3 8-phase GEMM + LN/score partials -----------------
__global__ __launch_bounds__(512, 2) void k_ff38(
    const _Float16* __restrict__ A, const _Float16* __restrict__ W,
    const float* __restrict__ bias, const float* __restrict__ ln_pre_g,
    const float* __restrict__ Ws, float* __restrict__ Pbuf){
  __shared__ _Float16 smA8[2][SMH];
  __shared__ _Float16 smB8[2][SMH];
  K8_SETUP(A, W)
  float gws[4], bv[4];
#pragma unroll
  for (int nf = 0; nf < 4; ++nf){
    int n = n0 + wn*64 + nf*16 + l15;
    gws[nf] = ln_pre_g[n]*Ws[n];
    bv[nf] = bias[n];
  }
  float* sP = (float*)&smB8[0][0];   // reuse: [256 rows][4 wn][3], 12 KB
#pragma unroll
  for (int mf = 0; mf < 8; ++mf){
#pragma unroll
    for (int r = 0; r < 4; ++r){
      float p1 = 0.f, p2 = 0.f, p3 = 0.f;
#pragma unroll
      for (int nf = 0; nf < 4; ++nf){
        float xv = fmaxf(acc[mf][nf][r] + bv[nf], 0.f);
        p1 += xv; p2 += xv*xv; p3 += gws[nf]*xv;
      }
#pragma unroll
      for (int off = 1; off < 16; off <<= 1){
        p1 += __shfl_xor(p1, off);
        p2 += __shfl_xor(p2, off);
        p3 += __shfl_xor(p3, off);
      }
      if (l15 == 0){
        int rl = wm*128 + mf*16 + q*4 + r;
        sP[(rl*4 + wn)*3 + 0] = p1;
        sP[(rl*4 + wn)*3 + 1] = p2;
        sP[(rl*4 + wn)*3 + 2] = p3;
      }
    }
  }
  __syncthreads();
  if (tid < 256){
    int m = m0 + tid;
    float* dst = Pbuf + ((size_t)m*2 + nt)*3;
#pragma unroll
    for (int c = 0; c < 3; ++c)
      dst[c] = sP[(tid*4+0)*3+c] + sP[(tid*4+1)*3+c] +
               sP[(tid*4+2)*3+c] + sP[(tid*4+3)*3+c];
  }
}

// ---------------- K4: finish scores from partials + zero spect --------------
__global__ __launch_bounds__(256) void k_score_fin(
    const float* __restrict__ Pbuf, const float* __restrict__ g,
    const float* __restrict__ bta, const float* __restrict__ Ws,
    const float* __restrict__ bs, float* __restrict__ scores,
    float* __restrict__ spect){
  __shared__ float red[8];
  int tid = threadIdx.x, lane = tid & 63, wv = tid >> 6;
  if (blockIdx.x < 32) spect[(size_t)blockIdx.x*256 + tid] = 0.f;
  int i0 = tid*2;
  float c1p = g[i0]*Ws[i0] + g[i0+1]*Ws[i0+1];
  float c2p = bta[i0]*Ws[i0] + bta[i0+1]*Ws[i0+1];
  c1p = wave_sum_f(c1p); c2p = wave_sum_f(c2p);
  if (lane == 0){ red[wv] = c1p; red[4+wv] = c2p; }
  __syncthreads();
  float c1 = red[0]+red[1]+red[2]+red[3];
  float c2 = red[4]+red[5]+red[6]+red[7] + bs[0];
  size_t row = (size_t)blockIdx.x*256 + tid;
  const float* p = Pbuf + row*6;
  float2 u0 = *(const float2*)p;
  float2 u1 = *(const float2*)(p+2);
  float2 u2 = *(const float2*)(p+4);
  float P1 = u0.x + u1.y;
  float P2 = u0.y + u2.x;
  float P3 = u1.x + u2.y;
  float mu = P1*(1.f/512.f);
  float var = P2*(1.f/512.f) - mu*mu;
  float rs = rsqrtf(var + 1e-5f);
  scores[row] = rs*(P3 - mu*c1) + c2;
}

// ---------------- K5: softmax over S per batch (1024 threads) ---------------
__global__ __launch_bounds__(1024) void k_softmax(
    const float* __restrict__ scores, float* __restrict__ probs){
  __shared__ float red[16];
  int b = blockIdx.x, tid = threadIdx.x, lane = tid & 63, wv = tid >> 6;
  const float* sp = scores + (size_t)b*S_;
  float* pp = probs + (size_t)b*S_;
  float mx = -1e30f;
  for (int i = tid; i < S_; i += 1024) mx = fmaxf(mx, sp[i]);
  mx = wave_max_f(mx);
  if (lane == 0) red[wv] = mx;
  __syncthreads();
  float m2 = red[0];
#pragma unroll
  for (int k = 1; k < 16; ++k) m2 = fmaxf(m2, red[k]);
  __syncthreads();
  float sum = 0.f;
  for (int i = tid; i < S_; i += 1024){
    float e = __expf(sp[i]-m2);
    pp[i] = e;
    sum += e;
  }
  sum = wave_sum_f(sum);
  if (lane == 0) red[wv] = sum;
  __syncthreads();
  float s2 = 0.f;
#pragma unroll
  for (int k = 0; k < 16; ++k) s2 += red[k];
  float inv = 1.f/s2;
  for (int i = tid; i < S_; i += 1024)
    pp[i] *= inv;
}

// ---------------- K6: spectrum scatter (parallelized 8x) --------------------
__global__ __launch_bounds__(256) void k_spect_p(
    const float* __restrict__ peaks, const float* __restrict__ probs,
    float* __restrict__ spect){
  __shared__ float bins[512];
  int b = blockIdx.x, chunk = blockIdx.y, tid = threadIdx.x;
  bins[tid] = 0.f; bins[tid+256] = 0.f;
  __syncthreads();
  int s0 = chunk*(S_/8);
  for (int i = tid; i < (S_/8)*M_; i += 256){
    int s = s0 + (i >> 3), m = i & 7;
    const float* pk = peaks + (((size_t)b*S_ + s)*M_ + m)*2;
    float mass = pk[0], inten = pk[1];
    float p = probs[(size_t)b*S_ + s];
    int bin = (int)rintf(mass);
    bin = min(max(bin, 0), 511);
    atomicAdd(&bins[bin], inten*p);
  }
  __syncthreads();
  atomicAdd(&spect[(size_t)b*512 + tid],       bins[tid]);
  atomicAdd(&spect[(size_t)b*512 + tid + 256], bins[tid+256]);
}

// ---------------- launcher --------------------------------------------------
extern "C" void kernel_launch(void* const* d_in, const int* in_sizes, int n_in,
                              void* d_out, int out_size, void* d_ws, size_t ws_size,
                              hipStream_t stream) {
  const float* vf       = (const float*)d_in[0];
  const float* mask     = (const float*)d_in[1];
  const float* eoh      = (const float*)d_in[2];
  const float* subs     = (const float*)d_in[4];
  const float* peaks    = (const float*)d_in[5];
  const float* ln_sub_g = (const float*)d_in[6];
  const float* ln_sub_b = (const float*)d_in[7];
  const float* W_ih     = (const float*)d_in[8];
  const float* W_hh     = (const float*)d_in[9];
  const float* b_ih     = (const float*)d_in[10];
  const float* b_hh     = (const float*)d_in[11];
  const float* W1       = (const float*)d_in[12];
  const float* b1       = (const float*)d_in[13];
  const float* W2a      = (const float*)d_in[14];
  const float* b2a      = (const float*)d_in[15];
  const float* W2b      = (const float*)d_in[16];
  const float* b2b      = (const float*)d_in[17];
  const float* ln_pre_g = (const float*)d_in[18];
  const float* ln_pre_b = (const float*)d_in[19];
  const float* Ws       = (const float*)d_in[20];
  const float* bs       = (const float*)d_in[21];
  float* out = (float*)d_out;            // [0,8192) spect, [8192,73728) probs
  float* probs_out = out + (size_t)B_*512;

  // workspace carve — ~158 MB (ws >= ~206 MB proven)
  char* w = (char*)d_ws;
  float* scores = (float*)w;     w += (size_t)BS_*4;
  float* Pbuf   = (float*)w;     w += (size_t)BS_*12*4;        // 3 MB (uses 6/row)
  _Float16* Wcat = (_Float16*)w; w += (size_t)NG_*KC_*2;       // ~2 MB
  _Float16* W1h  = (_Float16*)w; w += (size_t)G_*G_*2;
  _Float16* W2ah = (_Float16*)w; w += (size_t)G_*G_*2;
  _Float16* W2bh = (_Float16*)w; w += (size_t)G_*G_*2;
  _Float16* Abuf = (_Float16*)w; w += (size_t)BS_*KC_*2;       // 84 MB
  _Float16* bufh0 = (_Float16*)w;                              // 67 MB (H)
  _Float16* bufh1 = Abuf;        // x1 reuses A region (84 >= 67 MB)

  k_cvtw<<<dim3(256, 4), 256, 0, stream>>>(W1, W2a, W2b, W1h, W_hh, W_ih, Wcat);
  k_prep_mfma<<<dim3(S_/128, B_), 256, 0, stream>>>(vf, mask, eoh, subs,
                                                    ln_sub_g, ln_sub_b, Abuf);
  k_gru_fused<<<dim3(8, 512), 512, 0, stream>>>(Abuf, Wcat, b_ih, b_hh, bufh0);
  k_gemm8<<<512, 512, 0, stream>>>(bufh0, W1h,  b1,  bufh1);   // x1
  k_gemm8<<<512, 512, 0, stream>>>(bufh1, W2ah, b2a, bufh0);   // x2
  k_ff38<<<512, 512, 0, stream>>>(bufh0, W2bh, b2b, ln_pre_g, Ws, Pbuf);
  k_score_fin<<<BS_/256, 256, 0, stream>>>(Pbuf, ln_pre_g, ln_pre_b, Ws, bs,
                                           scores, out);
  k_softmax<<<B_, 1024, 0, stream>>>(scores, probs_out);
  k_spect_p<<<dim3(B_, 8), 256, 0, stream>>>(peaks, probs_out, out);
}